// Round 1
// baseline (4166.134 us; speedup 1.0000x reference)
//
#include <hip/hip_runtime.h>
#include <math.h>

#define B_SZ 2
#define L_SZ 1024
#define H_SZ 1024
#define NH_SZ 16
#define HD_SZ 64
#define DIN 2048
#define NST 16
#define KCONV 4
#define DTR 64

// ---------------------------------------------------------------------------
// Generic f32 GEMM: C[M,N] = A[M,K] (row stride lda) @ W[N,K]^T + bias
// 64x64 tile, BK=16, 256 threads, 4x4 microtile per thread.
// M must be multiple of 64 (always 2048 here); N may be ragged (guarded).
// K must be multiple of 16 (1024 / 2048 / 64 / 96-slice uses K=64).
// ---------------------------------------------------------------------------
__global__ __launch_bounds__(256) void sgemm_bias(
    const float* __restrict__ A, int lda,
    const float* __restrict__ W,
    const float* __restrict__ bias,
    float* __restrict__ C, int ldc,
    int M, int N, int K)
{
    __shared__ float As[16][64];
    __shared__ float Ws[16][64];
    const int tid = threadIdx.x;
    const int m0 = blockIdx.y * 64;
    const int n0 = blockIdx.x * 64;
    const int tr = tid >> 4;       // 0..15
    const int tc = tid & 15;       // 0..15
    const int lrow = tid >> 2;     // 0..63
    const int lk = (tid & 3) * 4;  // 0,4,8,12

    float acc[4][4] = {};

    for (int k0 = 0; k0 < K; k0 += 16) {
        // A tile
        const float* ap = A + (size_t)(m0 + lrow) * lda + k0 + lk;
        float4 av = *(const float4*)ap;
        As[lk + 0][lrow] = av.x;
        As[lk + 1][lrow] = av.y;
        As[lk + 2][lrow] = av.z;
        As[lk + 3][lrow] = av.w;
        // W tile (guard ragged N)
        float4 wv = make_float4(0.f, 0.f, 0.f, 0.f);
        if (n0 + lrow < N)
            wv = *(const float4*)(W + (size_t)(n0 + lrow) * K + k0 + lk);
        Ws[lk + 0][lrow] = wv.x;
        Ws[lk + 1][lrow] = wv.y;
        Ws[lk + 2][lrow] = wv.z;
        Ws[lk + 3][lrow] = wv.w;
        __syncthreads();
#pragma unroll
        for (int kk = 0; kk < 16; kk++) {
            float4 a4 = *(const float4*)&As[kk][tr * 4];
            float4 w4 = *(const float4*)&Ws[kk][tc * 4];
            float a[4] = {a4.x, a4.y, a4.z, a4.w};
            float w[4] = {w4.x, w4.y, w4.z, w4.w};
#pragma unroll
            for (int i = 0; i < 4; i++)
#pragma unroll
                for (int j = 0; j < 4; j++)
                    acc[i][j] = fmaf(a[i], w[j], acc[i][j]);
        }
        __syncthreads();
    }

#pragma unroll
    for (int i = 0; i < 4; i++) {
        int m = m0 + tr * 4 + i;
#pragma unroll
        for (int j = 0; j < 4; j++) {
            int n = n0 + tc * 4 + j;
            if (n < N) {
                float v = acc[i][j];
                if (bias) v += bias[n];
                C[(size_t)m * ldc + n] = v;
            }
        }
    }
}

// ---------------------------------------------------------------------------
// Fused attention: one 64-thread block per (b, h, qpos).
// scores -> (+mask) -> softmax -> P@V.  Never materializes B*NH*L*L.
// ---------------------------------------------------------------------------
__global__ __launch_bounds__(64) void attn_kernel(
    const float* __restrict__ q, const float* __restrict__ k,
    const float* __restrict__ v, const int* __restrict__ mask,
    float* __restrict__ ctx)
{
    const int bid = blockIdx.x;               // b*NH*L + h*L + qpos
    const int qpos = bid & (L_SZ - 1);
    const int h = (bid >> 10) & (NH_SZ - 1);
    const int b = bid >> 14;
    const int t = threadIdx.x;                // 0..63

    __shared__ float qs[HD_SZ];
    __shared__ float ss[L_SZ];

    qs[t] = q[(size_t)(b * L_SZ + qpos) * H_SZ + h * HD_SZ + t];
    __syncthreads();

    // scores: each thread computes 16 of the 1024 scores
    for (int kb = 0; kb < L_SZ / 64; kb++) {
        int kidx = kb * 64 + t;
        const float* kp = k + (size_t)(b * L_SZ + kidx) * H_SZ + h * HD_SZ;
        float dot = 0.f;
#pragma unroll 16
        for (int d = 0; d < HD_SZ; d++) dot = fmaf(qs[d], kp[d], dot);
        ss[kidx] = dot * 0.125f + (float)mask[b * L_SZ + kidx];
    }
    __syncthreads();

    // softmax over 1024 scores (single wave -> shuffles cover the block)
    float mx = -1e30f;
    for (int i = t; i < L_SZ; i += 64) mx = fmaxf(mx, ss[i]);
#pragma unroll
    for (int off = 32; off; off >>= 1) mx = fmaxf(mx, __shfl_down(mx, off));
    mx = __shfl(mx, 0);
    float sum = 0.f;
    for (int i = t; i < L_SZ; i += 64) {
        float e = expf(ss[i] - mx);
        ss[i] = e;
        sum += e;
    }
#pragma unroll
    for (int off = 32; off; off >>= 1) sum += __shfl_down(sum, off);
    sum = __shfl(sum, 0);
    float inv = 1.0f / sum;
    __syncthreads();

    // P @ V : thread t owns dim t of the 64-dim output
    float acc = 0.f;
    const float* vp = v + (size_t)(b * L_SZ) * H_SZ + h * HD_SZ + t;
    for (int kidx = 0; kidx < L_SZ; kidx++)
        acc = fmaf(ss[kidx], vp[(size_t)kidx * H_SZ], acc);
    ctx[(size_t)(b * L_SZ + qpos) * H_SZ + h * HD_SZ + t] = acc * inv;
}

// ---------------------------------------------------------------------------
__device__ __forceinline__ float block_sum256(float v) {
    __shared__ float red[4];
#pragma unroll
    for (int off = 32; off; off >>= 1) v += __shfl_down(v, off);
    __syncthreads();  // protect red against previous use
    if ((threadIdx.x & 63) == 0) red[threadIdx.x >> 6] = v;
    __syncthreads();
    return red[0] + red[1] + red[2] + red[3];
}

// x2 = LayerNorm(t_in + x_in; w,b) + x_in      (one block per row of H=1024)
__global__ __launch_bounds__(256) void add_ln_kernel(
    const float* __restrict__ t_in, const float* __restrict__ x_in,
    const float* __restrict__ w, const float* __restrict__ bparm,
    float* __restrict__ out)
{
    const int row = blockIdx.x;
    const int tid = threadIdx.x;
    const int c0 = tid * 4;
    float4 tv = *(const float4*)(t_in + (size_t)row * H_SZ + c0);
    float4 xv = *(const float4*)(x_in + (size_t)row * H_SZ + c0);
    float vals[4] = {tv.x + xv.x, tv.y + xv.y, tv.z + xv.z, tv.w + xv.w};
    float xr[4] = {xv.x, xv.y, xv.z, xv.w};
    float s = vals[0] + vals[1] + vals[2] + vals[3];
    float mu = block_sum256(s) * (1.0f / H_SZ);
    float vs = 0.f;
#pragma unroll
    for (int i = 0; i < 4; i++) {
        float d = vals[i] - mu;
        vs += d * d;
    }
    float var = block_sum256(vs) * (1.0f / H_SZ);
    float inv = rsqrtf(var + 1e-12f);
#pragma unroll
    for (int i = 0; i < 4; i++) {
        int c = c0 + i;
        out[(size_t)row * H_SZ + c] =
            (vals[i] - mu) * inv * w[c] + bparm[c] + xr[i];
    }
}

// out = rmsnorm(x [+ add]) * w     (one block per row of H=1024)
__global__ __launch_bounds__(256) void rmsnorm_kernel(
    const float* __restrict__ x, const float* __restrict__ add,
    const float* __restrict__ w, float* __restrict__ out)
{
    const int row = blockIdx.x;
    const int c0 = threadIdx.x * 4;
    float4 xv = *(const float4*)(x + (size_t)row * H_SZ + c0);
    float vals[4] = {xv.x, xv.y, xv.z, xv.w};
    if (add) {
        float4 av = *(const float4*)(add + (size_t)row * H_SZ + c0);
        vals[0] += av.x; vals[1] += av.y; vals[2] += av.z; vals[3] += av.w;
    }
    float s = vals[0]*vals[0] + vals[1]*vals[1] + vals[2]*vals[2] + vals[3]*vals[3];
    float ms = block_sum256(s) * (1.0f / H_SZ);
    float inv = rsqrtf(ms + 1e-6f);
#pragma unroll
    for (int i = 0; i < 4; i++) {
        int c = c0 + i;
        out[(size_t)row * H_SZ + c] = vals[i] * inv * w[c];
    }
}

// causal depthwise conv (K=4) + bias + SiLU + mask.  hs lives in proj[:, :2048].
__global__ __launch_bounds__(256) void conv_silu_kernel(
    const float* __restrict__ proj, const int* __restrict__ mask,
    const float* __restrict__ conv_w, const float* __restrict__ conv_b,
    float* __restrict__ ssm_in)
{
    const int idx = blockIdx.x * 256 + threadIdx.x;  // b*L*DIN + l*DIN + d
    const int d = idx & (DIN - 1);
    const int l = (idx >> 11) & (L_SZ - 1);
    const int b = idx >> 21;
    float acc = conv_b[d];
#pragma unroll
    for (int j = 0; j < KCONV; j++) {
        int lp = l - (KCONV - 1) + j;
        if (lp >= 0) {
            float hv = proj[(size_t)(b * L_SZ + lp) * (2 * DIN) + d] *
                       (float)mask[b * L_SZ + lp];
            acc = fmaf(hv, conv_w[d * KCONV + j], acc);
        }
    }
    float sg = 1.0f / (1.0f + expf(-acc));
    ssm_in[idx] = acc * sg * (float)mask[b * L_SZ + l];
}

// Selective scan, fused: softplus(dt), recurrence, D-skip, gate SiLU.
// 16 blocks of 256 threads; thread owns channel d, 16-state in registers.
__global__ __launch_bounds__(256) void scan_kernel(
    const float* __restrict__ dbc, const float* __restrict__ dt_lin,
    const float* __restrict__ dt_b, const float* __restrict__ A_log,
    const float* __restrict__ D_skip, const float* __restrict__ ssm_in,
    const float* __restrict__ proj, float* __restrict__ scan_out)
{
    const int b = blockIdx.x >> 3;
    const int d = (blockIdx.x & 7) * 256 + threadIdx.x;
    float Aa[NST];
#pragma unroll
    for (int n = 0; n < NST; n++) Aa[n] = -expf(A_log[d * NST + n]);
    float st[NST] = {};
    const float dsk = D_skip[d];
    const float dtb = dt_b[d];
    __shared__ float Bs[NST], Cs[NST];

    for (int l = 0; l < L_SZ; l++) {
        const size_t row = (size_t)(b * L_SZ + l);
        if (threadIdx.x < 16)
            Bs[threadIdx.x] = dbc[row * 96 + DTR + threadIdx.x];
        else if (threadIdx.x < 32)
            Cs[threadIdx.x - 16] = dbc[row * 96 + DTR + NST + (threadIdx.x - 16)];
        __syncthreads();

        float dtv = dt_lin[row * DIN + d] + dtb;
        dtv = (dtv > 20.f) ? dtv : log1pf(expf(dtv));
        float u = ssm_in[row * DIN + d];
        float du = dtv * u;
        float y = 0.f;
#pragma unroll
        for (int n = 0; n < NST; n++) {
            float dA = expf(dtv * Aa[n]);
            st[n] = fmaf(dA, st[n], du * Bs[n]);
            y = fmaf(st[n], Cs[n], y);
        }
        float g = proj[row * (2 * DIN) + DIN + d];
        float sg = g / (1.0f + expf(-g));
        scan_out[row * DIN + d] = (y + u * dsk) * sg;
        __syncthreads();
    }
}

// ---------------------------------------------------------------------------
extern "C" void kernel_launch(void* const* d_in, const int* in_sizes, int n_in,
                              void* d_out, int out_size, void* d_ws, size_t ws_size,
                              hipStream_t stream) {
    const float* x      = (const float*)d_in[0];
    const int*   mask   = (const int*)d_in[1];
    const float* Wq     = (const float*)d_in[2];
    const float* bq     = (const float*)d_in[3];
    const float* Wk     = (const float*)d_in[4];
    const float* bk     = (const float*)d_in[5];
    const float* Wv     = (const float*)d_in[6];
    const float* bv     = (const float*)d_in[7];
    const float* Wo     = (const float*)d_in[8];
    const float* bo     = (const float*)d_in[9];
    const float* ln_w   = (const float*)d_in[10];
    const float* ln_b   = (const float*)d_in[11];
    const float* mnw    = (const float*)d_in[12];
    const float* in_proj_w = (const float*)d_in[13];
    const float* conv_w = (const float*)d_in[14];
    const float* conv_b = (const float*)d_in[15];
    const float* x_proj_w = (const float*)d_in[16];
    const float* dt_proj_w = (const float*)d_in[17];
    const float* dt_proj_b = (const float*)d_in[18];
    const float* A_log  = (const float*)d_in[19];
    const float* D_skip = (const float*)d_in[20];
    const float* out_proj_w = (const float*)d_in[21];
    const float* fnw    = (const float*)d_in[22];
    float* out = (float*)d_out;

    float* ws = (float*)d_ws;
    const size_t F1 = 1u << 20;  // 1M floats
    // layout (floats): [0,8F) q|k|v|ctx  (later: attn_tmp at 0, then proj 0..8F)
    float* q    = ws + 0 * F1;
    float* kbuf = ws + 2 * F1;
    float* vbuf = ws + 4 * F1;
    float* ctx  = ws + 6 * F1;
    float* attn_tmp = ws + 0 * F1;  // reuses q (dead after attn)
    float* proj = ws + 0 * F1;      // reuses q..ctx (dead after LN)
    float* x2   = ws + 8 * F1;
    float* h    = ws + 10 * F1;
    float* ssm  = ws + 12 * F1;
    float* dbc  = ws + 16 * F1;
    float* dtl  = ws + 17 * F1;
    float* so   = ws + 21 * F1;
    float* x3   = ws + 25 * F1;
    (void)ws_size; (void)n_in; (void)in_sizes; (void)out_size;

    const int M = B_SZ * L_SZ;  // 2048
    dim3 blk(256);

    // QKV projections
    sgemm_bias<<<dim3(H_SZ / 64, M / 64), blk, 0, stream>>>(x, H_SZ, Wq, bq, q,    H_SZ, M, H_SZ, H_SZ);
    sgemm_bias<<<dim3(H_SZ / 64, M / 64), blk, 0, stream>>>(x, H_SZ, Wk, bk, kbuf, H_SZ, M, H_SZ, H_SZ);
    sgemm_bias<<<dim3(H_SZ / 64, M / 64), blk, 0, stream>>>(x, H_SZ, Wv, bv, vbuf, H_SZ, M, H_SZ, H_SZ);

    // attention
    attn_kernel<<<dim3(B_SZ * NH_SZ * L_SZ), dim3(64), 0, stream>>>(q, kbuf, vbuf, mask, ctx);

    // Wo projection + LN + residual
    sgemm_bias<<<dim3(H_SZ / 64, M / 64), blk, 0, stream>>>(ctx, H_SZ, Wo, bo, attn_tmp, H_SZ, M, H_SZ, H_SZ);
    add_ln_kernel<<<dim3(M), blk, 0, stream>>>(attn_tmp, x, ln_w, ln_b, x2);

    // mamba pre-norm + in_proj
    rmsnorm_kernel<<<dim3(M), blk, 0, stream>>>(x2, nullptr, mnw, h);
    sgemm_bias<<<dim3(2 * DIN / 64, M / 64), blk, 0, stream>>>(h, H_SZ, in_proj_w, nullptr, proj, 2 * DIN, M, 2 * DIN, H_SZ);

    // conv + silu + mask
    conv_silu_kernel<<<dim3(B_SZ * L_SZ * DIN / 256), blk, 0, stream>>>(proj, mask, conv_w, conv_b, ssm);

    // x_proj (N=96) and dt_proj (K=64 from dbc stride 96)
    sgemm_bias<<<dim3(2, M / 64), blk, 0, stream>>>(ssm, DIN, x_proj_w, nullptr, dbc, 96, M, 96, DIN);
    sgemm_bias<<<dim3(DIN / 64, M / 64), blk, 0, stream>>>(dbc, 96, dt_proj_w, nullptr, dtl, DIN, M, DIN, DTR);

    // selective scan (fused softplus + D-skip + gate)
    scan_kernel<<<dim3(B_SZ * DIN / 256), blk, 0, stream>>>(dbc, dtl, dt_proj_b, A_log, D_skip, ssm, proj, so);

    // out_proj + final residual + rmsnorm
    sgemm_bias<<<dim3(H_SZ / 64, M / 64), blk, 0, stream>>>(so, DIN, out_proj_w, nullptr, x3, H_SZ, M, H_SZ, DIN);
    rmsnorm_kernel<<<dim3(M), blk, 0, stream>>>(x2, x3, fnw, out);
}

// Round 2
// 2321.449 us; speedup vs baseline: 1.7946x; 1.7946x over previous
//
#include <hip/hip_runtime.h>
#include <math.h>

#define B_SZ 2
#define L_SZ 1024
#define H_SZ 1024
#define NH_SZ 16
#define HD_SZ 64
#define DIN 2048
#define NST 16
#define KCONV 4
#define DTR 64

#define NC 32   // number of scan chunks
#define CL 32   // chunk length (NC*CL == L_SZ)

// ---------------------------------------------------------------------------
// Generic f32 GEMM: C[M,N] = A[M,K] (row stride lda) @ W[N,K]^T + bias
// 64x64 tile, BK=16, 256 threads, 4x4 microtile per thread.
// ---------------------------------------------------------------------------
__global__ __launch_bounds__(256) void sgemm_bias(
    const float* __restrict__ A, int lda,
    const float* __restrict__ W,
    const float* __restrict__ bias,
    float* __restrict__ C, int ldc,
    int M, int N, int K)
{
    __shared__ float As[16][64];
    __shared__ float Ws[16][64];
    const int tid = threadIdx.x;
    const int m0 = blockIdx.y * 64;
    const int n0 = blockIdx.x * 64;
    const int tr = tid >> 4;       // 0..15
    const int tc = tid & 15;       // 0..15
    const int lrow = tid >> 2;     // 0..63
    const int lk = (tid & 3) * 4;  // 0,4,8,12

    float acc[4][4] = {};

    for (int k0 = 0; k0 < K; k0 += 16) {
        const float* ap = A + (size_t)(m0 + lrow) * lda + k0 + lk;
        float4 av = *(const float4*)ap;
        As[lk + 0][lrow] = av.x;
        As[lk + 1][lrow] = av.y;
        As[lk + 2][lrow] = av.z;
        As[lk + 3][lrow] = av.w;
        float4 wv = make_float4(0.f, 0.f, 0.f, 0.f);
        if (n0 + lrow < N)
            wv = *(const float4*)(W + (size_t)(n0 + lrow) * K + k0 + lk);
        Ws[lk + 0][lrow] = wv.x;
        Ws[lk + 1][lrow] = wv.y;
        Ws[lk + 2][lrow] = wv.z;
        Ws[lk + 3][lrow] = wv.w;
        __syncthreads();
#pragma unroll
        for (int kk = 0; kk < 16; kk++) {
            float4 a4 = *(const float4*)&As[kk][tr * 4];
            float4 w4 = *(const float4*)&Ws[kk][tc * 4];
            float a[4] = {a4.x, a4.y, a4.z, a4.w};
            float w[4] = {w4.x, w4.y, w4.z, w4.w};
#pragma unroll
            for (int i = 0; i < 4; i++)
#pragma unroll
                for (int j = 0; j < 4; j++)
                    acc[i][j] = fmaf(a[i], w[j], acc[i][j]);
        }
        __syncthreads();
    }

#pragma unroll
    for (int i = 0; i < 4; i++) {
        int m = m0 + tr * 4 + i;
#pragma unroll
        for (int j = 0; j < 4; j++) {
            int n = n0 + tc * 4 + j;
            if (n < N) {
                float v = acc[i][j];
                if (bias) v += bias[n];
                C[(size_t)m * ldc + n] = v;
            }
        }
    }
}

// ---------------------------------------------------------------------------
// Fused attention: one 64-thread block per (b, h, qpos).
// ---------------------------------------------------------------------------
__global__ __launch_bounds__(64) void attn_kernel(
    const float* __restrict__ q, const float* __restrict__ k,
    const float* __restrict__ v, const int* __restrict__ mask,
    float* __restrict__ ctx)
{
    const int bid = blockIdx.x;               // b*NH*L + h*L + qpos
    const int qpos = bid & (L_SZ - 1);
    const int h = (bid >> 10) & (NH_SZ - 1);
    const int b = bid >> 14;
    const int t = threadIdx.x;                // 0..63

    __shared__ float qs[HD_SZ];
    __shared__ float ss[L_SZ];

    qs[t] = q[(size_t)(b * L_SZ + qpos) * H_SZ + h * HD_SZ + t];
    __syncthreads();

    for (int kb = 0; kb < L_SZ / 64; kb++) {
        int kidx = kb * 64 + t;
        const float* kp = k + (size_t)(b * L_SZ + kidx) * H_SZ + h * HD_SZ;
        float dot = 0.f;
#pragma unroll 16
        for (int d = 0; d < HD_SZ; d++) dot = fmaf(qs[d], kp[d], dot);
        ss[kidx] = dot * 0.125f + (float)mask[b * L_SZ + kidx];
    }
    __syncthreads();

    float mx = -1e30f;
    for (int i = t; i < L_SZ; i += 64) mx = fmaxf(mx, ss[i]);
#pragma unroll
    for (int off = 32; off; off >>= 1) mx = fmaxf(mx, __shfl_down(mx, off));
    mx = __shfl(mx, 0);
    float sum = 0.f;
    for (int i = t; i < L_SZ; i += 64) {
        float e = expf(ss[i] - mx);
        ss[i] = e;
        sum += e;
    }
#pragma unroll
    for (int off = 32; off; off >>= 1) sum += __shfl_down(sum, off);
    sum = __shfl(sum, 0);
    float inv = 1.0f / sum;
    __syncthreads();

    float acc = 0.f;
    const float* vp = v + (size_t)(b * L_SZ) * H_SZ + h * HD_SZ + t;
    for (int kidx = 0; kidx < L_SZ; kidx++)
        acc = fmaf(ss[kidx], vp[(size_t)kidx * H_SZ], acc);
    ctx[(size_t)(b * L_SZ + qpos) * H_SZ + h * HD_SZ + t] = acc * inv;
}

// ---------------------------------------------------------------------------
__device__ __forceinline__ float block_sum256(float v) {
    __shared__ float red[4];
#pragma unroll
    for (int off = 32; off; off >>= 1) v += __shfl_down(v, off);
    __syncthreads();
    if ((threadIdx.x & 63) == 0) red[threadIdx.x >> 6] = v;
    __syncthreads();
    return red[0] + red[1] + red[2] + red[3];
}

__global__ __launch_bounds__(256) void add_ln_kernel(
    const float* __restrict__ t_in, const float* __restrict__ x_in,
    const float* __restrict__ w, const float* __restrict__ bparm,
    float* __restrict__ out)
{
    const int row = blockIdx.x;
    const int tid = threadIdx.x;
    const int c0 = tid * 4;
    float4 tv = *(const float4*)(t_in + (size_t)row * H_SZ + c0);
    float4 xv = *(const float4*)(x_in + (size_t)row * H_SZ + c0);
    float vals[4] = {tv.x + xv.x, tv.y + xv.y, tv.z + xv.z, tv.w + xv.w};
    float xr[4] = {xv.x, xv.y, xv.z, xv.w};
    float s = vals[0] + vals[1] + vals[2] + vals[3];
    float mu = block_sum256(s) * (1.0f / H_SZ);
    float vs = 0.f;
#pragma unroll
    for (int i = 0; i < 4; i++) {
        float d = vals[i] - mu;
        vs += d * d;
    }
    float var = block_sum256(vs) * (1.0f / H_SZ);
    float inv = rsqrtf(var + 1e-12f);
#pragma unroll
    for (int i = 0; i < 4; i++) {
        int c = c0 + i;
        out[(size_t)row * H_SZ + c] =
            (vals[i] - mu) * inv * w[c] + bparm[c] + xr[i];
    }
}

__global__ __launch_bounds__(256) void rmsnorm_kernel(
    const float* __restrict__ x, const float* __restrict__ add,
    const float* __restrict__ w, float* __restrict__ out)
{
    const int row = blockIdx.x;
    const int c0 = threadIdx.x * 4;
    float4 xv = *(const float4*)(x + (size_t)row * H_SZ + c0);
    float vals[4] = {xv.x, xv.y, xv.z, xv.w};
    if (add) {
        float4 av = *(const float4*)(add + (size_t)row * H_SZ + c0);
        vals[0] += av.x; vals[1] += av.y; vals[2] += av.z; vals[3] += av.w;
    }
    float s = vals[0]*vals[0] + vals[1]*vals[1] + vals[2]*vals[2] + vals[3]*vals[3];
    float ms = block_sum256(s) * (1.0f / H_SZ);
    float inv = rsqrtf(ms + 1e-6f);
#pragma unroll
    for (int i = 0; i < 4; i++) {
        int c = c0 + i;
        out[(size_t)row * H_SZ + c] = vals[i] * inv * w[c];
    }
}

__global__ __launch_bounds__(256) void conv_silu_kernel(
    const float* __restrict__ proj, const int* __restrict__ mask,
    const float* __restrict__ conv_w, const float* __restrict__ conv_b,
    float* __restrict__ ssm_in)
{
    const int idx = blockIdx.x * 256 + threadIdx.x;  // b*L*DIN + l*DIN + d
    const int d = idx & (DIN - 1);
    const int l = (idx >> 11) & (L_SZ - 1);
    const int b = idx >> 21;
    float acc = conv_b[d];
#pragma unroll
    for (int j = 0; j < KCONV; j++) {
        int lp = l - (KCONV - 1) + j;
        if (lp >= 0) {
            float hv = proj[(size_t)(b * L_SZ + lp) * (2 * DIN) + d] *
                       (float)mask[b * L_SZ + lp];
            acc = fmaf(hv, conv_w[d * KCONV + j], acc);
        }
    }
    float sg = 1.0f / (1.0f + expf(-acc));
    ssm_in[idx] = acc * sg * (float)mask[b * L_SZ + l];
}

// ---------------------------------------------------------------------------
// Chunked selective scan.
// Pass 1: per chunk (zero init), compute P = prod dA and S = local final state.
// Combine: sequential over chunks (parallel over channels), emit init states.
// Pass 2: re-run recurrence from init state, fused y/D-skip/gate-SiLU.
// Layout of P/S/I: [b][c][n][d]  -> ((b*NC + c)*NST + n)*DIN + d  (coalesced in d)
// ---------------------------------------------------------------------------
__device__ __forceinline__ float softplus_f(float x) {
    return (x > 20.f) ? x : log1pf(expf(x));
}

__global__ __launch_bounds__(256) void scan_pass1(
    const float* __restrict__ dt_lin, const float* __restrict__ dt_b,
    const float* __restrict__ A_log, const float* __restrict__ dbc,
    const float* __restrict__ ssm_in,
    float* __restrict__ P, float* __restrict__ S)
{
    const int g = blockIdx.x & 7;             // channel group
    const int c = (blockIdx.x >> 3) & (NC - 1);
    const int b = blockIdx.x >> 8;
    const int d = g * 256 + threadIdx.x;
    const int row0 = b * L_SZ + c * CL;

    __shared__ float BCs[CL][32];             // [l][j]; j<16 = B, j>=16 = C
#pragma unroll
    for (int it = 0; it < (CL * 32) / 256; it++) {
        int i = threadIdx.x + it * 256;
        int l = i >> 5, j = i & 31;
        BCs[l][j] = dbc[(size_t)(row0 + l) * 96 + DTR + j];
    }
    __syncthreads();

    float Aa[NST];
#pragma unroll
    for (int n = 0; n < NST; n++) Aa[n] = -expf(A_log[d * NST + n]);
    const float dtb = dt_b[d];

    float st[NST] = {};
    float Pv[NST];
#pragma unroll
    for (int n = 0; n < NST; n++) Pv[n] = 1.0f;

    for (int l = 0; l < CL; l++) {
        const size_t row = (size_t)(row0 + l);
        float dtv = softplus_f(dt_lin[row * DIN + d] + dtb);
        float u = ssm_in[row * DIN + d];
        float du = dtv * u;
#pragma unroll
        for (int n = 0; n < NST; n++) {
            float dA = expf(dtv * Aa[n]);
            st[n] = fmaf(dA, st[n], du * BCs[l][n]);
            Pv[n] *= dA;
        }
    }
    const size_t base = ((size_t)(b * NC + c) * NST) * DIN + d;
#pragma unroll
    for (int n = 0; n < NST; n++) {
        P[base + (size_t)n * DIN] = Pv[n];
        S[base + (size_t)n * DIN] = st[n];
    }
}

__global__ __launch_bounds__(256) void scan_combine(
    const float* __restrict__ P, const float* __restrict__ S,
    float* __restrict__ I)
{
    const int idx = blockIdx.x * 256 + threadIdx.x;  // b*DIN + d
    const int b = idx >> 11;
    const int d = idx & (DIN - 1);
    float st[NST] = {};
    for (int c = 0; c < NC; c++) {
        const size_t base = ((size_t)(b * NC + c) * NST) * DIN + d;
#pragma unroll
        for (int n = 0; n < NST; n++) {
            const size_t o = base + (size_t)n * DIN;
            I[o] = st[n];
            st[n] = fmaf(P[o], st[n], S[o]);
        }
    }
}

__global__ __launch_bounds__(256) void scan_pass2(
    const float* __restrict__ dt_lin, const float* __restrict__ dt_b,
    const float* __restrict__ A_log, const float* __restrict__ dbc,
    const float* __restrict__ ssm_in, const float* __restrict__ I,
    const float* __restrict__ D_skip, const float* __restrict__ proj,
    float* __restrict__ scan_out)
{
    const int g = blockIdx.x & 7;
    const int c = (blockIdx.x >> 3) & (NC - 1);
    const int b = blockIdx.x >> 8;
    const int d = g * 256 + threadIdx.x;
    const int row0 = b * L_SZ + c * CL;

    __shared__ float BCs[CL][32];
#pragma unroll
    for (int it = 0; it < (CL * 32) / 256; it++) {
        int i = threadIdx.x + it * 256;
        int l = i >> 5, j = i & 31;
        BCs[l][j] = dbc[(size_t)(row0 + l) * 96 + DTR + j];
    }
    __syncthreads();

    float Aa[NST];
#pragma unroll
    for (int n = 0; n < NST; n++) Aa[n] = -expf(A_log[d * NST + n]);
    const float dtb = dt_b[d];
    const float dsk = D_skip[d];

    float st[NST];
    const size_t ibase = ((size_t)(b * NC + c) * NST) * DIN + d;
#pragma unroll
    for (int n = 0; n < NST; n++) st[n] = I[ibase + (size_t)n * DIN];

    for (int l = 0; l < CL; l++) {
        const size_t row = (size_t)(row0 + l);
        float dtv = softplus_f(dt_lin[row * DIN + d] + dtb);
        float u = ssm_in[row * DIN + d];
        float du = dtv * u;
        float y = 0.f;
#pragma unroll
        for (int n = 0; n < NST; n++) {
            float dA = expf(dtv * Aa[n]);
            st[n] = fmaf(dA, st[n], du * BCs[l][n]);
            y = fmaf(st[n], BCs[l][NST + n], y);
        }
        float gv = proj[row * (2 * DIN) + DIN + d];
        float sg = gv / (1.0f + expf(-gv));
        scan_out[row * DIN + d] = (y + u * dsk) * sg;
    }
}

// ---------------------------------------------------------------------------
extern "C" void kernel_launch(void* const* d_in, const int* in_sizes, int n_in,
                              void* d_out, int out_size, void* d_ws, size_t ws_size,
                              hipStream_t stream) {
    const float* x      = (const float*)d_in[0];
    const int*   mask   = (const int*)d_in[1];
    const float* Wq     = (const float*)d_in[2];
    const float* bq     = (const float*)d_in[3];
    const float* Wk     = (const float*)d_in[4];
    const float* bk     = (const float*)d_in[5];
    const float* Wv     = (const float*)d_in[6];
    const float* bv     = (const float*)d_in[7];
    const float* Wo     = (const float*)d_in[8];
    const float* bo     = (const float*)d_in[9];
    const float* ln_w   = (const float*)d_in[10];
    const float* ln_b   = (const float*)d_in[11];
    const float* mnw    = (const float*)d_in[12];
    const float* in_proj_w = (const float*)d_in[13];
    const float* conv_w = (const float*)d_in[14];
    const float* conv_b = (const float*)d_in[15];
    const float* x_proj_w = (const float*)d_in[16];
    const float* dt_proj_w = (const float*)d_in[17];
    const float* dt_proj_b = (const float*)d_in[18];
    const float* A_log  = (const float*)d_in[19];
    const float* D_skip = (const float*)d_in[20];
    const float* out_proj_w = (const float*)d_in[21];
    const float* fnw    = (const float*)d_in[22];
    float* out = (float*)d_out;

    float* ws = (float*)d_ws;
    const size_t F1 = 1u << 20;  // 1M floats
    float* q    = ws + 0 * F1;
    float* kbuf = ws + 2 * F1;
    float* vbuf = ws + 4 * F1;
    float* ctx  = ws + 6 * F1;
    float* attn_tmp = ws + 0 * F1;  // reuses q (dead after attn)
    float* proj = ws + 0 * F1;      // reuses q..ctx (dead after LN)
    float* x2   = ws + 8 * F1;
    float* h    = ws + 10 * F1;     // dead after in_proj -> reused for P
    float* ssm  = ws + 12 * F1;
    float* dbc  = ws + 16 * F1;
    float* dtl  = ws + 17 * F1;
    float* so   = ws + 21 * F1;
    float* x3   = ws + 25 * F1;
    float* Pbuf = ws + 10 * F1;     // 2M floats (aliases dead h)
    float* Sbuf = ws + 27 * F1;     // 2M floats
    float* Ibuf = ws + 29 * F1;     // 2M floats
    (void)ws_size; (void)n_in; (void)in_sizes; (void)out_size;

    const int M = B_SZ * L_SZ;  // 2048
    dim3 blk(256);

    // QKV projections
    sgemm_bias<<<dim3(H_SZ / 64, M / 64), blk, 0, stream>>>(x, H_SZ, Wq, bq, q,    H_SZ, M, H_SZ, H_SZ);
    sgemm_bias<<<dim3(H_SZ / 64, M / 64), blk, 0, stream>>>(x, H_SZ, Wk, bk, kbuf, H_SZ, M, H_SZ, H_SZ);
    sgemm_bias<<<dim3(H_SZ / 64, M / 64), blk, 0, stream>>>(x, H_SZ, Wv, bv, vbuf, H_SZ, M, H_SZ, H_SZ);

    // attention
    attn_kernel<<<dim3(B_SZ * NH_SZ * L_SZ), dim3(64), 0, stream>>>(q, kbuf, vbuf, mask, ctx);

    // Wo projection + LN + residual
    sgemm_bias<<<dim3(H_SZ / 64, M / 64), blk, 0, stream>>>(ctx, H_SZ, Wo, bo, attn_tmp, H_SZ, M, H_SZ, H_SZ);
    add_ln_kernel<<<dim3(M), blk, 0, stream>>>(attn_tmp, x, ln_w, ln_b, x2);

    // mamba pre-norm + in_proj
    rmsnorm_kernel<<<dim3(M), blk, 0, stream>>>(x2, nullptr, mnw, h);
    sgemm_bias<<<dim3(2 * DIN / 64, M / 64), blk, 0, stream>>>(h, H_SZ, in_proj_w, nullptr, proj, 2 * DIN, M, 2 * DIN, H_SZ);

    // conv + silu + mask
    conv_silu_kernel<<<dim3(B_SZ * L_SZ * DIN / 256), blk, 0, stream>>>(proj, mask, conv_w, conv_b, ssm);

    // x_proj (N=96) and dt_proj (K=64 from dbc stride 96)
    sgemm_bias<<<dim3(2, M / 64), blk, 0, stream>>>(ssm, DIN, x_proj_w, nullptr, dbc, 96, M, 96, DIN);
    sgemm_bias<<<dim3(DIN / 64, M / 64), blk, 0, stream>>>(dbc, 96, dt_proj_w, nullptr, dtl, DIN, M, DIN, DTR);

    // chunked selective scan
    scan_pass1<<<dim3(B_SZ * NC * (DIN / 256)), blk, 0, stream>>>(dtl, dt_proj_b, A_log, dbc, ssm, Pbuf, Sbuf);
    scan_combine<<<dim3(B_SZ * DIN / 256), blk, 0, stream>>>(Pbuf, Sbuf, Ibuf);
    scan_pass2<<<dim3(B_SZ * NC * (DIN / 256)), blk, 0, stream>>>(dtl, dt_proj_b, A_log, dbc, ssm, Ibuf, D_skip, proj, so);

    // out_proj + final residual + rmsnorm
    sgemm_bias<<<dim3(H_SZ / 64, M / 64), blk, 0, stream>>>(so, DIN, out_proj_w, nullptr, x3, H_SZ, M, H_SZ, DIN);
    rmsnorm_kernel<<<dim3(M), blk, 0, stream>>>(x2, x3, fnw, out);
}

// Round 3
// 1800.095 us; speedup vs baseline: 2.3144x; 1.2896x over previous
//
#include <hip/hip_runtime.h>
#include <math.h>

#define B_SZ 2
#define L_SZ 1024
#define H_SZ 1024
#define NH_SZ 16
#define HD_SZ 64
#define DIN 2048
#define NST 16
#define KCONV 4
#define DTR 64

#define NC 32   // scan chunks
#define CL 32   // chunk length

typedef _Float16 half8v __attribute__((ext_vector_type(8)));
typedef _Float16 half4v __attribute__((ext_vector_type(4)));
typedef float floatx4 __attribute__((ext_vector_type(4)));

// ---------------------------------------------------------------------------
// MFMA f16 GEMM: C[M,N] = A[M,K] @ W[N,K]^T + bias.  M mult of 128, K mult 32.
// 128x128 tile, BK=32, 256 threads = 4 waves, each wave 64x64 (4x4 MFMA tiles).
// ---------------------------------------------------------------------------
__global__ __launch_bounds__(256) void hgemm(
    const _Float16* __restrict__ A, int lda,
    const _Float16* __restrict__ W, int ldw,
    const float* __restrict__ bias,
    float* __restrict__ C, int ldc,
    int N, int K)
{
    __shared__ __align__(16) _Float16 As[128 * 32];
    __shared__ __align__(16) _Float16 Bs[128 * 32];
    const int tid = threadIdx.x;
    const int m0 = blockIdx.y * 128;
    const int n0 = blockIdx.x * 128;
    const int wave = tid >> 6;
    const int lane = tid & 63;
    const int wm = (wave >> 1) * 64;
    const int wn = (wave & 1) * 64;
    const int row_l = tid >> 2;            // 0..63
    const int col_l = (tid & 3) * 8;       // 0,8,16,24

    floatx4 zero = {0.f, 0.f, 0.f, 0.f};
    floatx4 acc[4][4];
#pragma unroll
    for (int i = 0; i < 4; i++)
#pragma unroll
        for (int j = 0; j < 4; j++) acc[i][j] = zero;

    const int fr = lane & 15;
    const int fq = (lane >> 4) * 8;

    for (int k0 = 0; k0 < K; k0 += 32) {
        *(half8v*)&As[row_l * 32 + col_l] =
            *(const half8v*)&A[(size_t)(m0 + row_l) * lda + k0 + col_l];
        *(half8v*)&As[(row_l + 64) * 32 + col_l] =
            *(const half8v*)&A[(size_t)(m0 + row_l + 64) * lda + k0 + col_l];
        *(half8v*)&Bs[row_l * 32 + col_l] =
            *(const half8v*)&W[(size_t)(n0 + row_l) * ldw + k0 + col_l];
        *(half8v*)&Bs[(row_l + 64) * 32 + col_l] =
            *(const half8v*)&W[(size_t)(n0 + row_l + 64) * ldw + k0 + col_l];
        __syncthreads();

        half8v af[4], bf[4];
#pragma unroll
        for (int i = 0; i < 4; i++)
            af[i] = *(const half8v*)&As[(wm + i * 16 + fr) * 32 + fq];
#pragma unroll
        for (int j = 0; j < 4; j++)
            bf[j] = *(const half8v*)&Bs[(wn + j * 16 + fr) * 32 + fq];
#pragma unroll
        for (int i = 0; i < 4; i++)
#pragma unroll
            for (int j = 0; j < 4; j++)
                acc[i][j] = __builtin_amdgcn_mfma_f32_16x16x32_f16(
                    af[i], bf[j], acc[i][j], 0, 0, 0);
        __syncthreads();
    }

    // C/D layout (16x16): col = lane&15, row = (lane>>4)*4 + reg
    const int er = (lane >> 4) * 4;
    const int ec = lane & 15;
#pragma unroll
    for (int j = 0; j < 4; j++) {
        int n = n0 + wn + j * 16 + ec;
        if (n < N) {
            float bv = bias ? bias[n] : 0.f;
#pragma unroll
            for (int i = 0; i < 4; i++) {
#pragma unroll
                for (int r = 0; r < 4; r++) {
                    int m = m0 + wm + i * 16 + er + r;
                    C[(size_t)m * ldc + n] = acc[i][j][r] + bv;
                }
            }
        }
    }
}

// ---------------------------------------------------------------------------
// cast helpers
// ---------------------------------------------------------------------------
__global__ __launch_bounds__(256) void cast_f2h_kernel(
    const float* __restrict__ s, _Float16* __restrict__ d, int n)
{
    int i = (blockIdx.x * 256 + threadIdx.x) * 4;
    if (i < n) {
        float4 v = *(const float4*)&s[i];
        half4v o = {(_Float16)v.x, (_Float16)v.y, (_Float16)v.z, (_Float16)v.w};
        *(half4v*)&d[i] = o;
    }
}

// pad x_proj_w [96,2048] -> [128,2048] f16 (zero rows 96..127)
__global__ __launch_bounds__(256) void cast_pad_xproj_kernel(
    const float* __restrict__ s, _Float16* __restrict__ d)
{
    int i = blockIdx.x * 256 + threadIdx.x;   // 128*2048
    int r = i >> 11;
    d[i] = (r < 96) ? (_Float16)s[i] : (_Float16)0.f;
}

// pack dbc[:, :64] (stride 96) -> [2048,64] f16
__global__ __launch_bounds__(256) void pack_dbc_kernel(
    const float* __restrict__ s, _Float16* __restrict__ d)
{
    int i = blockIdx.x * 256 + threadIdx.x;   // 2048*64
    int r = i >> 6, c = i & 63;
    d[i] = (_Float16)s[r * 96 + c];
}

// ---------------------------------------------------------------------------
// Attention: 2 q-rows per 128-thread block; K tile staged in LDS (padded).
// ---------------------------------------------------------------------------
__global__ __launch_bounds__(128) void attn_kernel(
    const float* __restrict__ q, const float* __restrict__ k,
    const float* __restrict__ v, const int* __restrict__ mask,
    float* __restrict__ ctx)
{
    const int bid = blockIdx.x;               // b*NH*512 + h*512 + qp2
    const int qp2 = bid & 511;
    const int h = (bid >> 9) & (NH_SZ - 1);
    const int b = bid >> 13;
    const int t = threadIdx.x;
    const int wave = t >> 6;
    const int lane = t & 63;
    const int qpos = qp2 * 2 + wave;

    __shared__ float qs[2][HD_SZ];
    __shared__ float Kt[64][65];
    __shared__ float ss[2][L_SZ];

    qs[wave][lane] = q[(size_t)(b * L_SZ + qpos) * H_SZ + h * HD_SZ + lane];

    for (int kb = 0; kb < L_SZ / 64; kb++) {
        __syncthreads();
        // stage K tile 64x64 (coalesced global, padded LDS rows)
#pragma unroll
        for (int i = 0; i < 8; i++) {
            int lin = i * 512 + t * 4;
            int r = lin >> 6, c = lin & 63;
            float4 kv = *(const float4*)&k[(size_t)(b * L_SZ + kb * 64 + r) * H_SZ + h * HD_SZ + c];
            Kt[r][c + 0] = kv.x;
            Kt[r][c + 1] = kv.y;
            Kt[r][c + 2] = kv.z;
            Kt[r][c + 3] = kv.w;
        }
        __syncthreads();
        int kidx = kb * 64 + lane;
        float dot = 0.f;
#pragma unroll 16
        for (int d = 0; d < HD_SZ; d++)
            dot = fmaf(Kt[lane][d], qs[wave][d], dot);
        ss[wave][kidx] = dot * 0.125f + (float)mask[b * L_SZ + kidx];
    }
    __syncthreads();

    // per-wave softmax over 1024 scores
    float* sw = ss[wave];
    float mx = -1e30f;
    for (int i = lane; i < L_SZ; i += 64) mx = fmaxf(mx, sw[i]);
#pragma unroll
    for (int off = 32; off; off >>= 1) mx = fmaxf(mx, __shfl_down(mx, off));
    mx = __shfl(mx, 0);
    float sum = 0.f;
    for (int i = lane; i < L_SZ; i += 64) {
        float e = expf(sw[i] - mx);
        sw[i] = e;
        sum += e;
    }
#pragma unroll
    for (int off = 32; off; off >>= 1) sum += __shfl_down(sum, off);
    sum = __shfl(sum, 0);
    float inv = 1.0f / sum;

    // P @ V (coalesced V reads)
    float acc = 0.f;
    const float* vp = v + (size_t)(b * L_SZ) * H_SZ + h * HD_SZ + lane;
#pragma unroll 4
    for (int kidx = 0; kidx < L_SZ; kidx++)
        acc = fmaf(sw[kidx], vp[(size_t)kidx * H_SZ], acc);
    ctx[(size_t)(b * L_SZ + qpos) * H_SZ + h * HD_SZ + lane] = acc * inv;
}

// ---------------------------------------------------------------------------
__device__ __forceinline__ float block_sum256(float v) {
    __shared__ float red[4];
#pragma unroll
    for (int off = 32; off; off >>= 1) v += __shfl_down(v, off);
    __syncthreads();
    if ((threadIdx.x & 63) == 0) red[threadIdx.x >> 6] = v;
    __syncthreads();
    return red[0] + red[1] + red[2] + red[3];
}

__global__ __launch_bounds__(256) void add_ln_kernel(
    const float* __restrict__ t_in, const float* __restrict__ x_in,
    const float* __restrict__ w, const float* __restrict__ bparm,
    float* __restrict__ out)
{
    const int row = blockIdx.x;
    const int c0 = threadIdx.x * 4;
    float4 tv = *(const float4*)(t_in + (size_t)row * H_SZ + c0);
    float4 xv = *(const float4*)(x_in + (size_t)row * H_SZ + c0);
    float vals[4] = {tv.x + xv.x, tv.y + xv.y, tv.z + xv.z, tv.w + xv.w};
    float xr[4] = {xv.x, xv.y, xv.z, xv.w};
    float s = vals[0] + vals[1] + vals[2] + vals[3];
    float mu = block_sum256(s) * (1.0f / H_SZ);
    float vs = 0.f;
#pragma unroll
    for (int i = 0; i < 4; i++) {
        float d = vals[i] - mu;
        vs += d * d;
    }
    float var = block_sum256(vs) * (1.0f / H_SZ);
    float inv = rsqrtf(var + 1e-12f);
#pragma unroll
    for (int i = 0; i < 4; i++) {
        int c = c0 + i;
        out[(size_t)row * H_SZ + c] =
            (vals[i] - mu) * inv * w[c] + bparm[c] + xr[i];
    }
}

// rmsnorm -> f16 output
__global__ __launch_bounds__(256) void rmsnorm_h_kernel(
    const float* __restrict__ x, const float* __restrict__ w,
    _Float16* __restrict__ out)
{
    const int row = blockIdx.x;
    const int c0 = threadIdx.x * 4;
    float4 xv = *(const float4*)(x + (size_t)row * H_SZ + c0);
    float vals[4] = {xv.x, xv.y, xv.z, xv.w};
    float s = vals[0]*vals[0] + vals[1]*vals[1] + vals[2]*vals[2] + vals[3]*vals[3];
    float ms = block_sum256(s) * (1.0f / H_SZ);
    float inv = rsqrtf(ms + 1e-6f);
    half4v o;
#pragma unroll
    for (int i = 0; i < 4; i++) o[i] = (_Float16)(vals[i] * inv * w[c0 + i]);
    *(half4v*)&out[(size_t)row * H_SZ + c0] = o;
}

// rmsnorm(x + add) -> f32 output
__global__ __launch_bounds__(256) void rmsnorm_kernel(
    const float* __restrict__ x, const float* __restrict__ add,
    const float* __restrict__ w, float* __restrict__ out)
{
    const int row = blockIdx.x;
    const int c0 = threadIdx.x * 4;
    float4 xv = *(const float4*)(x + (size_t)row * H_SZ + c0);
    float vals[4] = {xv.x, xv.y, xv.z, xv.w};
    if (add) {
        float4 av = *(const float4*)(add + (size_t)row * H_SZ + c0);
        vals[0] += av.x; vals[1] += av.y; vals[2] += av.z; vals[3] += av.w;
    }
    float s = vals[0]*vals[0] + vals[1]*vals[1] + vals[2]*vals[2] + vals[3]*vals[3];
    float ms = block_sum256(s) * (1.0f / H_SZ);
    float inv = rsqrtf(ms + 1e-6f);
#pragma unroll
    for (int i = 0; i < 4; i++) {
        int c = c0 + i;
        out[(size_t)row * H_SZ + c] = vals[i] * inv * w[c];
    }
}

// conv + bias + silu + mask; writes f32 (for scan u) and f16 (for x_proj A)
__global__ __launch_bounds__(256) void conv_silu_kernel(
    const float* __restrict__ proj, const int* __restrict__ mask,
    const float* __restrict__ conv_w, const float* __restrict__ conv_b,
    float* __restrict__ ssm_f, _Float16* __restrict__ ssm_h)
{
    const int idx = blockIdx.x * 256 + threadIdx.x;  // b*L*DIN + l*DIN + d
    const int d = idx & (DIN - 1);
    const int l = (idx >> 11) & (L_SZ - 1);
    const int b = idx >> 21;
    float acc = conv_b[d];
#pragma unroll
    for (int j = 0; j < KCONV; j++) {
        int lp = l - (KCONV - 1) + j;
        if (lp >= 0) {
            float hv = proj[(size_t)(b * L_SZ + lp) * (2 * DIN) + d] *
                       (float)mask[b * L_SZ + lp];
            acc = fmaf(hv, conv_w[d * KCONV + j], acc);
        }
    }
    float sg = 1.0f / (1.0f + expf(-acc));
    float r = acc * sg * (float)mask[b * L_SZ + l];
    ssm_f[idx] = r;
    ssm_h[idx] = (_Float16)r;
}

// ---------------------------------------------------------------------------
// Chunked selective scan (as round 2, pass2 emits f16 for out_proj A)
// ---------------------------------------------------------------------------
__device__ __forceinline__ float softplus_f(float x) {
    return (x > 20.f) ? x : log1pf(expf(x));
}

__global__ __launch_bounds__(256) void scan_pass1(
    const float* __restrict__ dt_lin, const float* __restrict__ dt_b,
    const float* __restrict__ A_log, const float* __restrict__ dbc,
    const float* __restrict__ ssm_in,
    float* __restrict__ P, float* __restrict__ S)
{
    const int g = blockIdx.x & 7;
    const int c = (blockIdx.x >> 3) & (NC - 1);
    const int b = blockIdx.x >> 8;
    const int d = g * 256 + threadIdx.x;
    const int row0 = b * L_SZ + c * CL;

    __shared__ float BCs[CL][32];
#pragma unroll
    for (int it = 0; it < (CL * 32) / 256; it++) {
        int i = threadIdx.x + it * 256;
        int l = i >> 5, j = i & 31;
        BCs[l][j] = dbc[(size_t)(row0 + l) * 96 + DTR + j];
    }
    __syncthreads();

    float Aa[NST];
#pragma unroll
    for (int n = 0; n < NST; n++) Aa[n] = -expf(A_log[d * NST + n]);
    const float dtb = dt_b[d];

    float st[NST] = {};
    float Pv[NST];
#pragma unroll
    for (int n = 0; n < NST; n++) Pv[n] = 1.0f;

    for (int l = 0; l < CL; l++) {
        const size_t row = (size_t)(row0 + l);
        float dtv = softplus_f(dt_lin[row * DIN + d] + dtb);
        float u = ssm_in[row * DIN + d];
        float du = dtv * u;
#pragma unroll
        for (int n = 0; n < NST; n++) {
            float dA = expf(dtv * Aa[n]);
            st[n] = fmaf(dA, st[n], du * BCs[l][n]);
            Pv[n] *= dA;
        }
    }
    const size_t base = ((size_t)(b * NC + c) * NST) * DIN + d;
#pragma unroll
    for (int n = 0; n < NST; n++) {
        P[base + (size_t)n * DIN] = Pv[n];
        S[base + (size_t)n * DIN] = st[n];
    }
}

// I may alias P (read-before-write per element)
__global__ __launch_bounds__(256) void scan_combine(
    const float* __restrict__ P, const float* __restrict__ S,
    float* __restrict__ I)
{
    const int idx = blockIdx.x * 256 + threadIdx.x;  // b*DIN + d
    const int b = idx >> 11;
    const int d = idx & (DIN - 1);
    float st[NST] = {};
    for (int c = 0; c < NC; c++) {
        const size_t base = ((size_t)(b * NC + c) * NST) * DIN + d;
#pragma unroll
        for (int n = 0; n < NST; n++) {
            const size_t o = base + (size_t)n * DIN;
            float pv = P[o], sv = S[o];
            I[o] = st[n];
            st[n] = fmaf(pv, st[n], sv);
        }
    }
}

__global__ __launch_bounds__(256) void scan_pass2(
    const float* __restrict__ dt_lin, const float* __restrict__ dt_b,
    const float* __restrict__ A_log, const float* __restrict__ dbc,
    const float* __restrict__ ssm_in, const float* __restrict__ I,
    const float* __restrict__ D_skip, const float* __restrict__ proj,
    _Float16* __restrict__ scan_out)
{
    const int g = blockIdx.x & 7;
    const int c = (blockIdx.x >> 3) & (NC - 1);
    const int b = blockIdx.x >> 8;
    const int d = g * 256 + threadIdx.x;
    const int row0 = b * L_SZ + c * CL;

    __shared__ float BCs[CL][32];
#pragma unroll
    for (int it = 0; it < (CL * 32) / 256; it++) {
        int i = threadIdx.x + it * 256;
        int l = i >> 5, j = i & 31;
        BCs[l][j] = dbc[(size_t)(row0 + l) * 96 + DTR + j];
    }
    __syncthreads();

    float Aa[NST];
#pragma unroll
    for (int n = 0; n < NST; n++) Aa[n] = -expf(A_log[d * NST + n]);
    const float dtb = dt_b[d];
    const float dsk = D_skip[d];

    float st[NST];
    const size_t ibase = ((size_t)(b * NC + c) * NST) * DIN + d;
#pragma unroll
    for (int n = 0; n < NST; n++) st[n] = I[ibase + (size_t)n * DIN];

    for (int l = 0; l < CL; l++) {
        const size_t row = (size_t)(row0 + l);
        float dtv = softplus_f(dt_lin[row * DIN + d] + dtb);
        float u = ssm_in[row * DIN + d];
        float du = dtv * u;
        float y = 0.f;
#pragma unroll
        for (int n = 0; n < NST; n++) {
            float dA = expf(dtv * Aa[n]);
            st[n] = fmaf(dA, st[n], du * BCs[l][n]);
            y = fmaf(st[n], BCs[l][NST + n], y);
        }
        float gv = proj[row * (2 * DIN) + DIN + d];
        float sg = gv / (1.0f + expf(-gv));
        scan_out[row * DIN + d] = (_Float16)((y + u * dsk) * sg);
    }
}

// ---------------------------------------------------------------------------
extern "C" void kernel_launch(void* const* d_in, const int* in_sizes, int n_in,
                              void* d_out, int out_size, void* d_ws, size_t ws_size,
                              hipStream_t stream) {
    const float* x      = (const float*)d_in[0];
    const int*   mask   = (const int*)d_in[1];
    const float* Wq     = (const float*)d_in[2];
    const float* bq     = (const float*)d_in[3];
    const float* Wk     = (const float*)d_in[4];
    const float* bk     = (const float*)d_in[5];
    const float* Wv     = (const float*)d_in[6];
    const float* bv     = (const float*)d_in[7];
    const float* Wo     = (const float*)d_in[8];
    const float* bo     = (const float*)d_in[9];
    const float* ln_w   = (const float*)d_in[10];
    const float* ln_b   = (const float*)d_in[11];
    const float* mnw    = (const float*)d_in[12];
    const float* in_proj_w = (const float*)d_in[13];
    const float* conv_w = (const float*)d_in[14];
    const float* conv_b = (const float*)d_in[15];
    const float* x_proj_w = (const float*)d_in[16];
    const float* dt_proj_w = (const float*)d_in[17];
    const float* dt_proj_b = (const float*)d_in[18];
    const float* A_log  = (const float*)d_in[19];
    const float* D_skip = (const float*)d_in[20];
    const float* out_proj_w = (const float*)d_in[21];
    const float* fnw    = (const float*)d_in[22];
    float* out = (float*)d_out;
    (void)ws_size; (void)n_in; (void)in_sizes; (void)out_size;

    float* ws = (float*)d_ws;
    const size_t F1 = 1u << 20;
    // f16 weight caches (re-cast every call)
    _Float16* Wqh  = (_Float16*)(ws + 0);
    _Float16* Wkh  = (_Float16*)(ws + F1 / 2);
    _Float16* Wvh  = (_Float16*)(ws + F1);
    _Float16* Woh  = (_Float16*)(ws + F1 * 3 / 2);
    _Float16* inph = (_Float16*)(ws + 2 * F1);
    _Float16* outph= (_Float16*)(ws + 4 * F1);
    _Float16* xprh = (_Float16*)(ws + 5 * F1);              // padded 128x2048
    _Float16* dtph = (_Float16*)(ws + 5 * F1 + F1 / 8);
    _Float16* xh   = (_Float16*)(ws + 5 * F1 + F1 / 4);     // [5.25F,6.25F)
    float* x2      = ws + 6 * F1 + F1 / 4;                  // [6.25F,8.25F)
    float* proj    = ws + 8 * F1 + F1 / 2;                  // [8.5F,16.5F)
    float* q       = proj;
    float* kbuf    = proj + 2 * F1;
    float* vbuf    = proj + 4 * F1;
    float* ctx     = proj + 6 * F1;
    float* x3      = proj;                                  // after pass2
    _Float16* ctxh = (_Float16*)(ws + 16 * F1 + F1 / 2);    // [16.5F,17.5F)
    _Float16* dbch = (_Float16*)(ws + 16 * F1 + F1 / 2);    // reuse (ctxh dead)
    float* dbc     = ws + 16 * F1 + 3 * F1 / 4;             // [16.75F,~16.94F)
    float* attn_tmp= ws + 17 * F1 + F1 / 2;                 // [17.5F,19.5F)
    _Float16* ssmh = (_Float16*)attn_tmp;                   // reuse
    float* Pbuf    = attn_tmp;                              // reuse (ssmh dead)
    float* Ibuf    = Pbuf;                                  // alias P (safe)
    _Float16* hh   = (_Float16*)(ws + 19 * F1 + F1 / 2);    // [19.5F,20.5F)
    float* ssm     = ws + 20 * F1 + F1 / 2;                 // [20.5F,24.5F)
    float* dtl     = ws + 24 * F1 + F1 / 2;                 // [24.5F,28.5F)
    float* Sbuf    = ws + 28 * F1 + F1 / 2;                 // [28.5F,30.5F)
    _Float16* sob  = (_Float16*)Sbuf;                       // reuse (S dead)

    const int M = B_SZ * L_SZ;  // 2048
    dim3 blk(256);

    // --- casts (weights + input) ---
    cast_f2h_kernel<<<1024, blk, 0, stream>>>(Wq, Wqh, H_SZ * H_SZ);
    cast_f2h_kernel<<<1024, blk, 0, stream>>>(Wk, Wkh, H_SZ * H_SZ);
    cast_f2h_kernel<<<1024, blk, 0, stream>>>(Wv, Wvh, H_SZ * H_SZ);
    cast_f2h_kernel<<<1024, blk, 0, stream>>>(Wo, Woh, H_SZ * H_SZ);
    cast_f2h_kernel<<<4096, blk, 0, stream>>>(in_proj_w, inph, 2 * DIN * H_SZ);
    cast_f2h_kernel<<<2048, blk, 0, stream>>>(out_proj_w, outph, H_SZ * DIN);
    cast_pad_xproj_kernel<<<1024, blk, 0, stream>>>(x_proj_w, xprh);
    cast_f2h_kernel<<<128, blk, 0, stream>>>(dt_proj_w, dtph, DIN * DTR);
    cast_f2h_kernel<<<2048, blk, 0, stream>>>(x, xh, M * H_SZ);

    // --- QKV ---
    hgemm<<<dim3(8, 16), blk, 0, stream>>>(xh, H_SZ, Wqh, H_SZ, bq, q,    H_SZ, H_SZ, H_SZ);
    hgemm<<<dim3(8, 16), blk, 0, stream>>>(xh, H_SZ, Wkh, H_SZ, bk, kbuf, H_SZ, H_SZ, H_SZ);
    hgemm<<<dim3(8, 16), blk, 0, stream>>>(xh, H_SZ, Wvh, H_SZ, bv, vbuf, H_SZ, H_SZ, H_SZ);

    // --- attention ---
    attn_kernel<<<dim3(B_SZ * NH_SZ * (L_SZ / 2)), dim3(128), 0, stream>>>(q, kbuf, vbuf, mask, ctx);
    cast_f2h_kernel<<<2048, blk, 0, stream>>>(ctx, ctxh, M * H_SZ);

    // --- Wo + LN + residual ---
    hgemm<<<dim3(8, 16), blk, 0, stream>>>(ctxh, H_SZ, Woh, H_SZ, bo, attn_tmp, H_SZ, H_SZ, H_SZ);
    add_ln_kernel<<<dim3(M), blk, 0, stream>>>(attn_tmp, x, ln_w, ln_b, x2);

    // --- mamba pre-norm + in_proj ---
    rmsnorm_h_kernel<<<dim3(M), blk, 0, stream>>>(x2, mnw, hh);
    hgemm<<<dim3(32, 16), blk, 0, stream>>>(hh, H_SZ, inph, H_SZ, nullptr, proj, 2 * DIN, 2 * DIN, H_SZ);

    // --- conv + silu ---
    conv_silu_kernel<<<dim3(B_SZ * L_SZ * DIN / 256), blk, 0, stream>>>(proj, mask, conv_w, conv_b, ssm, ssmh);

    // --- x_proj (N=96, padded W) and dt_proj ---
    hgemm<<<dim3(1, 16), blk, 0, stream>>>(ssmh, DIN, xprh, DIN, nullptr, dbc, 96, 96, DIN);
    pack_dbc_kernel<<<512, blk, 0, stream>>>(dbc, dbch);
    hgemm<<<dim3(16, 16), blk, 0, stream>>>(dbch, DTR, dtph, DTR, nullptr, dtl, DIN, DIN, DTR);

    // --- chunked scan ---
    scan_pass1<<<dim3(B_SZ * NC * (DIN / 256)), blk, 0, stream>>>(dtl, dt_proj_b, A_log, dbc, ssm, Pbuf, Sbuf);
    scan_combine<<<dim3(B_SZ * DIN / 256), blk, 0, stream>>>(Pbuf, Sbuf, Ibuf);
    scan_pass2<<<dim3(B_SZ * NC * (DIN / 256)), blk, 0, stream>>>(dtl, dt_proj_b, A_log, dbc, ssm, Ibuf, D_skip, proj, sob);

    // --- out_proj + final norm ---
    hgemm<<<dim3(8, 16), blk, 0, stream>>>(sob, DIN, outph, DIN, nullptr, x3, H_SZ, H_SZ, DIN);
    rmsnorm_kernel<<<dim3(M), blk, 0, stream>>>(x2, x3, fnw, out);
}

// Round 4
// 691.796 us; speedup vs baseline: 6.0222x; 2.6021x over previous
//
#include <hip/hip_runtime.h>
#include <math.h>

#define B_SZ 2
#define L_SZ 1024
#define H_SZ 1024
#define NH_SZ 16
#define HD_SZ 64
#define DIN 2048
#define NST 16
#define KCONV 4
#define DTR 64

#define NC 32   // scan chunks
#define CL 32   // chunk length

typedef _Float16 half8v __attribute__((ext_vector_type(8)));
typedef _Float16 half4v __attribute__((ext_vector_type(4)));
typedef _Float16 half2v __attribute__((ext_vector_type(2)));
typedef float floatx4 __attribute__((ext_vector_type(4)));

// ---------------------------------------------------------------------------
// MFMA f16 GEMM: C[M,N] = A[M,K] @ W[N,K]^T + bias.  M mult of 128, K mult 32.
// ---------------------------------------------------------------------------
__global__ __launch_bounds__(256) void hgemm(
    const _Float16* __restrict__ A, int lda,
    const _Float16* __restrict__ W, int ldw,
    const float* __restrict__ bias,
    float* __restrict__ C, int ldc,
    int N, int K)
{
    __shared__ __align__(16) _Float16 As[128 * 32];
    __shared__ __align__(16) _Float16 Bs[128 * 32];
    const int tid = threadIdx.x;
    const int m0 = blockIdx.y * 128;
    const int n0 = blockIdx.x * 128;
    const int wave = tid >> 6;
    const int lane = tid & 63;
    const int wm = (wave >> 1) * 64;
    const int wn = (wave & 1) * 64;
    const int row_l = tid >> 2;
    const int col_l = (tid & 3) * 8;

    floatx4 zero = {0.f, 0.f, 0.f, 0.f};
    floatx4 acc[4][4];
#pragma unroll
    for (int i = 0; i < 4; i++)
#pragma unroll
        for (int j = 0; j < 4; j++) acc[i][j] = zero;

    const int fr = lane & 15;
    const int fq = (lane >> 4) * 8;

    for (int k0 = 0; k0 < K; k0 += 32) {
        *(half8v*)&As[row_l * 32 + col_l] =
            *(const half8v*)&A[(size_t)(m0 + row_l) * lda + k0 + col_l];
        *(half8v*)&As[(row_l + 64) * 32 + col_l] =
            *(const half8v*)&A[(size_t)(m0 + row_l + 64) * lda + k0 + col_l];
        *(half8v*)&Bs[row_l * 32 + col_l] =
            *(const half8v*)&W[(size_t)(n0 + row_l) * ldw + k0 + col_l];
        *(half8v*)&Bs[(row_l + 64) * 32 + col_l] =
            *(const half8v*)&W[(size_t)(n0 + row_l + 64) * ldw + k0 + col_l];
        __syncthreads();

        half8v af[4], bf[4];
#pragma unroll
        for (int i = 0; i < 4; i++)
            af[i] = *(const half8v*)&As[(wm + i * 16 + fr) * 32 + fq];
#pragma unroll
        for (int j = 0; j < 4; j++)
            bf[j] = *(const half8v*)&Bs[(wn + j * 16 + fr) * 32 + fq];
#pragma unroll
        for (int i = 0; i < 4; i++)
#pragma unroll
            for (int j = 0; j < 4; j++)
                acc[i][j] = __builtin_amdgcn_mfma_f32_16x16x32_f16(
                    af[i], bf[j], acc[i][j], 0, 0, 0);
        __syncthreads();
    }

    const int er = (lane >> 4) * 4;
    const int ec = lane & 15;
#pragma unroll
    for (int j = 0; j < 4; j++) {
        int n = n0 + wn + j * 16 + ec;
        if (n < N) {
            float bv = bias ? bias[n] : 0.f;
#pragma unroll
            for (int i = 0; i < 4; i++) {
#pragma unroll
                for (int r = 0; r < 4; r++) {
                    int m = m0 + wm + i * 16 + er + r;
                    C[(size_t)m * ldc + n] = acc[i][j][r] + bv;
                }
            }
        }
    }
}

// ---------------------------------------------------------------------------
// cast / repack helpers
// ---------------------------------------------------------------------------
__global__ __launch_bounds__(256) void cast_f2h_kernel(
    const float* __restrict__ s, _Float16* __restrict__ d, int n)
{
    int i = (blockIdx.x * 256 + threadIdx.x) * 4;
    if (i < n) {
        float4 v = *(const float4*)&s[i];
        half4v o = {(_Float16)v.x, (_Float16)v.y, (_Float16)v.z, (_Float16)v.w};
        *(half4v*)&d[i] = o;
    }
}

__global__ __launch_bounds__(256) void cast_pad_xproj_kernel(
    const float* __restrict__ s, _Float16* __restrict__ d)
{
    int i = blockIdx.x * 256 + threadIdx.x;   // 128*2048
    int r = i >> 11;
    d[i] = (r < 96) ? (_Float16)s[i] : (_Float16)0.f;
}

__global__ __launch_bounds__(256) void pack_dbc_kernel(
    const float* __restrict__ s, _Float16* __restrict__ d)
{
    int i = blockIdx.x * 256 + threadIdx.x;   // 2048*64
    int r = i >> 6, c = i & 63;
    d[i] = (_Float16)s[r * 96 + c];
}

// q,k f32 [b][l][h*64+hd] -> f16 [b][h][l][hd]
__global__ __launch_bounds__(256) void repack_qk_kernel(
    const float* __restrict__ qf, const float* __restrict__ kf,
    _Float16* __restrict__ qh, _Float16* __restrict__ kh)
{
    int e = (blockIdx.x * 256 + threadIdx.x) * 4;   // output element id
    int hd = e & 63;
    int l  = (e >> 6) & (L_SZ - 1);
    int h  = (e >> 16) & (NH_SZ - 1);
    int b  = e >> 20;
    size_t src = ((size_t)(b * L_SZ + l) * NH_SZ + h) * HD_SZ + hd;
    float4 vq = *(const float4*)&qf[src];
    float4 vk = *(const float4*)&kf[src];
    half4v oq = {(_Float16)vq.x, (_Float16)vq.y, (_Float16)vq.z, (_Float16)vq.w};
    half4v ok = {(_Float16)vk.x, (_Float16)vk.y, (_Float16)vk.z, (_Float16)vk.w};
    *(half4v*)&qh[e] = oq;
    *(half4v*)&kh[e] = ok;
}

// v f32 [b][l][h*64+hd] -> f16 transposed [b][h][hd][l]
__global__ __launch_bounds__(256) void vtrans_kernel(
    const float* __restrict__ vf, _Float16* __restrict__ vth)
{
    const int lt = blockIdx.x & 15;
    const int h  = (blockIdx.x >> 4) & (NH_SZ - 1);
    const int b  = blockIdx.x >> 8;
    __shared__ float Vf[64 * 65];
    const int tid = threadIdx.x;
#pragma unroll
    for (int p = 0; p < 4; p++) {
        int lin = p * 1024 + tid * 4;
        int r = lin >> 6, c = lin & 63;   // r = l, c = hd
        float4 t4 = *(const float4*)&vf[((size_t)(b * L_SZ + lt * 64 + r) * NH_SZ + h) * HD_SZ + c];
        Vf[r * 65 + c + 0] = t4.x;
        Vf[r * 65 + c + 1] = t4.y;
        Vf[r * 65 + c + 2] = t4.z;
        Vf[r * 65 + c + 3] = t4.w;
    }
    __syncthreads();
    const int hd = tid >> 2;
    const int l0 = (tid & 3) * 16;
    _Float16* dst = vth + ((size_t)(b * NH_SZ + h) * HD_SZ + hd) * L_SZ + lt * 64 + l0;
#pragma unroll
    for (int kk = 0; kk < 16; kk += 2) {
        half2v o = {(_Float16)Vf[(l0 + kk) * 65 + hd],
                    (_Float16)Vf[(l0 + kk + 1) * 65 + hd]};
        *(half2v*)&dst[kk] = o;
    }
}

// ---------------------------------------------------------------------------
// MFMA flash attention: block = (b, h, 64-row q tile); 4 waves x 16 q rows.
// ---------------------------------------------------------------------------
__global__ __launch_bounds__(256) void attn_mfma(
    const _Float16* __restrict__ qh, const _Float16* __restrict__ kh,
    const _Float16* __restrict__ vth, const int* __restrict__ mask,
    float* __restrict__ ctx)
{
    const int qt = blockIdx.x & 15;
    const int h  = (blockIdx.x >> 4) & (NH_SZ - 1);
    const int b  = blockIdx.x >> 8;
    const int tid = threadIdx.x;
    const int wave = tid >> 6;
    const int lane = tid & 63;
    const int fr = lane & 15;          // frag row (m/n) and C col
    const int g  = lane >> 4;
    const int fq = g * 8;              // frag k offset
    const int g4 = g * 4;              // C row base

    __shared__ __align__(16) _Float16 Qs[64 * 72];
    __shared__ __align__(16) _Float16 Ks[64 * 72];
    __shared__ __align__(16) _Float16 Vs[64 * 72];
    __shared__ __align__(16) _Float16 Ps[4][16 * 72];

    const _Float16* qbase = qh + ((size_t)(b * NH_SZ + h) * L_SZ + qt * 64) * HD_SZ;
    const _Float16* kbase = kh + (size_t)(b * NH_SZ + h) * L_SZ * HD_SZ;
    const _Float16* vbase = vth + (size_t)(b * NH_SZ + h) * HD_SZ * L_SZ;

    // stage Q tile (64x64 f16)
#pragma unroll
    for (int p = 0; p < 2; p++) {
        int lin = p * 2048 + tid * 8;
        int r = lin >> 6, c = lin & 63;
        *(half8v*)&Qs[r * 72 + c] = *(const half8v*)&qbase[r * 64 + c];
    }
    __syncthreads();
    half8v aQ[2];
    aQ[0] = *(const half8v*)&Qs[(wave * 16 + fr) * 72 + 0 + fq];
    aQ[1] = *(const half8v*)&Qs[(wave * 16 + fr) * 72 + 32 + fq];

    float m_run[4] = {-1e30f, -1e30f, -1e30f, -1e30f};
    float l_run[4] = {0.f, 0.f, 0.f, 0.f};
    floatx4 zero = {0.f, 0.f, 0.f, 0.f};
    floatx4 accO[4];
#pragma unroll
    for (int jn = 0; jn < 4; jn++) accO[jn] = zero;

    for (int kb = 0; kb < L_SZ / 64; kb++) {
        __syncthreads();   // protect Ks/Vs from previous iteration readers
#pragma unroll
        for (int p = 0; p < 2; p++) {
            int lin = p * 2048 + tid * 8;
            int r = lin >> 6, c = lin & 63;
            *(half8v*)&Ks[r * 72 + c] = *(const half8v*)&kbase[(kb * 64 + r) * 64 + c];
            *(half8v*)&Vs[r * 72 + c] = *(const half8v*)&vbase[(size_t)r * L_SZ + kb * 64 + c];
        }
        __syncthreads();

        // S tile = Q @ K^T  (wave's 16 rows x 64 keys)
        floatx4 sc[4];
#pragma unroll
        for (int jn = 0; jn < 4; jn++) {
            half8v bk0 = *(const half8v*)&Ks[(jn * 16 + fr) * 72 + 0 + fq];
            half8v bk1 = *(const half8v*)&Ks[(jn * 16 + fr) * 72 + 32 + fq];
            floatx4 t = __builtin_amdgcn_mfma_f32_16x16x32_f16(aQ[0], bk0, zero, 0, 0, 0);
            sc[jn] = __builtin_amdgcn_mfma_f32_16x16x32_f16(aQ[1], bk1, t, 0, 0, 0);
        }

        // scale + mask
        float s[4][4], p[4][4];
#pragma unroll
        for (int jn = 0; jn < 4; jn++) {
            float ml = (float)mask[b * L_SZ + kb * 64 + jn * 16 + fr];
#pragma unroll
            for (int r = 0; r < 4; r++) s[jn][r] = sc[jn][r] * 0.125f + ml;
        }
        // online softmax (rows live across 16-lane group)
#pragma unroll
        for (int r = 0; r < 4; r++) {
            float tm = fmaxf(fmaxf(s[0][r], s[1][r]), fmaxf(s[2][r], s[3][r]));
#pragma unroll
            for (int off = 1; off < 16; off <<= 1) tm = fmaxf(tm, __shfl_xor(tm, off));
            float mn = fmaxf(m_run[r], tm);
            float alpha = expf(m_run[r] - mn);
            float rs = 0.f;
#pragma unroll
            for (int jn = 0; jn < 4; jn++) {
                float pv = expf(s[jn][r] - mn);
                p[jn][r] = pv;
                rs += pv;
            }
#pragma unroll
            for (int off = 1; off < 16; off <<= 1) rs += __shfl_xor(rs, off);
            l_run[r] = l_run[r] * alpha + rs;
            m_run[r] = mn;
#pragma unroll
            for (int jn = 0; jn < 4; jn++) accO[jn][r] *= alpha;
        }
        // P -> LDS (C layout -> A layout round trip; per-wave region)
#pragma unroll
        for (int jn = 0; jn < 4; jn++)
#pragma unroll
            for (int r = 0; r < 4; r++)
                Ps[wave][(g4 + r) * 72 + jn * 16 + fr] = (_Float16)p[jn][r];
        __syncthreads();

        // O += P @ V
        half8v aP0 = *(const half8v*)&Ps[wave][fr * 72 + 0 + fq];
        half8v aP1 = *(const half8v*)&Ps[wave][fr * 72 + 32 + fq];
#pragma unroll
        for (int jn = 0; jn < 4; jn++) {
            half8v bv0 = *(const half8v*)&Vs[(jn * 16 + fr) * 72 + 0 + fq];
            half8v bv1 = *(const half8v*)&Vs[(jn * 16 + fr) * 72 + 32 + fq];
            accO[jn] = __builtin_amdgcn_mfma_f32_16x16x32_f16(aP0, bv0, accO[jn], 0, 0, 0);
            accO[jn] = __builtin_amdgcn_mfma_f32_16x16x32_f16(aP1, bv1, accO[jn], 0, 0, 0);
        }
    }

    // epilogue: O / l
#pragma unroll
    for (int jn = 0; jn < 4; jn++) {
#pragma unroll
        for (int r = 0; r < 4; r++) {
            int qrow = qt * 64 + wave * 16 + g4 + r;
            ctx[((size_t)(b * L_SZ) + qrow) * H_SZ + h * 64 + jn * 16 + fr] =
                accO[jn][r] / l_run[r];
        }
    }
}

// ---------------------------------------------------------------------------
__device__ __forceinline__ float block_sum256(float v) {
    __shared__ float red[4];
#pragma unroll
    for (int off = 32; off; off >>= 1) v += __shfl_down(v, off);
    __syncthreads();
    if ((threadIdx.x & 63) == 0) red[threadIdx.x >> 6] = v;
    __syncthreads();
    return red[0] + red[1] + red[2] + red[3];
}

__global__ __launch_bounds__(256) void add_ln_kernel(
    const float* __restrict__ t_in, const float* __restrict__ x_in,
    const float* __restrict__ w, const float* __restrict__ bparm,
    float* __restrict__ out)
{
    const int row = blockIdx.x;
    const int c0 = threadIdx.x * 4;
    float4 tv = *(const float4*)(t_in + (size_t)row * H_SZ + c0);
    float4 xv = *(const float4*)(x_in + (size_t)row * H_SZ + c0);
    float vals[4] = {tv.x + xv.x, tv.y + xv.y, tv.z + xv.z, tv.w + xv.w};
    float xr[4] = {xv.x, xv.y, xv.z, xv.w};
    float s = vals[0] + vals[1] + vals[2] + vals[3];
    float mu = block_sum256(s) * (1.0f / H_SZ);
    float vs = 0.f;
#pragma unroll
    for (int i = 0; i < 4; i++) {
        float d = vals[i] - mu;
        vs += d * d;
    }
    float var = block_sum256(vs) * (1.0f / H_SZ);
    float inv = rsqrtf(var + 1e-12f);
#pragma unroll
    for (int i = 0; i < 4; i++) {
        int c = c0 + i;
        out[(size_t)row * H_SZ + c] =
            (vals[i] - mu) * inv * w[c] + bparm[c] + xr[i];
    }
}

__global__ __launch_bounds__(256) void rmsnorm_h_kernel(
    const float* __restrict__ x, const float* __restrict__ w,
    _Float16* __restrict__ out)
{
    const int row = blockIdx.x;
    const int c0 = threadIdx.x * 4;
    float4 xv = *(const float4*)(x + (size_t)row * H_SZ + c0);
    float vals[4] = {xv.x, xv.y, xv.z, xv.w};
    float s = vals[0]*vals[0] + vals[1]*vals[1] + vals[2]*vals[2] + vals[3]*vals[3];
    float ms = block_sum256(s) * (1.0f / H_SZ);
    float inv = rsqrtf(ms + 1e-6f);
    half4v o;
#pragma unroll
    for (int i = 0; i < 4; i++) o[i] = (_Float16)(vals[i] * inv * w[c0 + i]);
    *(half4v*)&out[(size_t)row * H_SZ + c0] = o;
}

__global__ __launch_bounds__(256) void rmsnorm_kernel(
    const float* __restrict__ x, const float* __restrict__ add,
    const float* __restrict__ w, float* __restrict__ out)
{
    const int row = blockIdx.x;
    const int c0 = threadIdx.x * 4;
    float4 xv = *(const float4*)(x + (size_t)row * H_SZ + c0);
    float vals[4] = {xv.x, xv.y, xv.z, xv.w};
    if (add) {
        float4 av = *(const float4*)(add + (size_t)row * H_SZ + c0);
        vals[0] += av.x; vals[1] += av.y; vals[2] += av.z; vals[3] += av.w;
    }
    float s = vals[0]*vals[0] + vals[1]*vals[1] + vals[2]*vals[2] + vals[3]*vals[3];
    float ms = block_sum256(s) * (1.0f / H_SZ);
    float inv = rsqrtf(ms + 1e-6f);
#pragma unroll
    for (int i = 0; i < 4; i++) {
        int c = c0 + i;
        out[(size_t)row * H_SZ + c] = vals[i] * inv * w[c];
    }
}

__global__ __launch_bounds__(256) void conv_silu_kernel(
    const float* __restrict__ proj, const int* __restrict__ mask,
    const float* __restrict__ conv_w, const float* __restrict__ conv_b,
    float* __restrict__ ssm_f, _Float16* __restrict__ ssm_h)
{
    const int idx = blockIdx.x * 256 + threadIdx.x;  // b*L*DIN + l*DIN + d
    const int d = idx & (DIN - 1);
    const int l = (idx >> 11) & (L_SZ - 1);
    const int b = idx >> 21;
    float acc = conv_b[d];
#pragma unroll
    for (int j = 0; j < KCONV; j++) {
        int lp = l - (KCONV - 1) + j;
        if (lp >= 0) {
            float hv = proj[(size_t)(b * L_SZ + lp) * (2 * DIN) + d] *
                       (float)mask[b * L_SZ + lp];
            acc = fmaf(hv, conv_w[d * KCONV + j], acc);
        }
    }
    float sg = 1.0f / (1.0f + expf(-acc));
    float r = acc * sg * (float)mask[b * L_SZ + l];
    ssm_f[idx] = r;
    ssm_h[idx] = (_Float16)r;
}

// ---------------------------------------------------------------------------
// Chunked selective scan
// ---------------------------------------------------------------------------
__device__ __forceinline__ float softplus_f(float x) {
    return (x > 20.f) ? x : log1pf(expf(x));
}

__global__ __launch_bounds__(256) void scan_pass1(
    const float* __restrict__ dt_lin, const float* __restrict__ dt_b,
    const float* __restrict__ A_log, const float* __restrict__ dbc,
    const float* __restrict__ ssm_in,
    float* __restrict__ P, float* __restrict__ S)
{
    const int g = blockIdx.x & 7;
    const int c = (blockIdx.x >> 3) & (NC - 1);
    const int b = blockIdx.x >> 8;
    const int d = g * 256 + threadIdx.x;
    const int row0 = b * L_SZ + c * CL;

    __shared__ float BCs[CL][32];
#pragma unroll
    for (int it = 0; it < (CL * 32) / 256; it++) {
        int i = threadIdx.x + it * 256;
        int l = i >> 5, j = i & 31;
        BCs[l][j] = dbc[(size_t)(row0 + l) * 96 + DTR + j];
    }
    __syncthreads();

    float Aa[NST];
#pragma unroll
    for (int n = 0; n < NST; n++) Aa[n] = -expf(A_log[d * NST + n]);
    const float dtb = dt_b[d];

    float st[NST] = {};
    float Pv[NST];
#pragma unroll
    for (int n = 0; n < NST; n++) Pv[n] = 1.0f;

    for (int l = 0; l < CL; l++) {
        const size_t row = (size_t)(row0 + l);
        float dtv = softplus_f(dt_lin[row * DIN + d] + dtb);
        float u = ssm_in[row * DIN + d];
        float du = dtv * u;
#pragma unroll
        for (int n = 0; n < NST; n++) {
            float dA = expf(dtv * Aa[n]);
            st[n] = fmaf(dA, st[n], du * BCs[l][n]);
            Pv[n] *= dA;
        }
    }
    const size_t base = ((size_t)(b * NC + c) * NST) * DIN + d;
#pragma unroll
    for (int n = 0; n < NST; n++) {
        P[base + (size_t)n * DIN] = Pv[n];
        S[base + (size_t)n * DIN] = st[n];
    }
}

__global__ __launch_bounds__(256) void scan_combine(
    const float* __restrict__ P, const float* __restrict__ S,
    float* __restrict__ I)
{
    const int idx = blockIdx.x * 256 + threadIdx.x;  // b*DIN + d
    const int b = idx >> 11;
    const int d = idx & (DIN - 1);
    float st[NST] = {};
    for (int c = 0; c < NC; c++) {
        const size_t base = ((size_t)(b * NC + c) * NST) * DIN + d;
#pragma unroll
        for (int n = 0; n < NST; n++) {
            const size_t o = base + (size_t)n * DIN;
            float pv = P[o], sv = S[o];
            I[o] = st[n];
            st[n] = fmaf(pv, st[n], sv);
        }
    }
}

__global__ __launch_bounds__(256) void scan_pass2(
    const float* __restrict__ dt_lin, const float* __restrict__ dt_b,
    const float* __restrict__ A_log, const float* __restrict__ dbc,
    const float* __restrict__ ssm_in, const float* __restrict__ I,
    const float* __restrict__ D_skip, const float* __restrict__ proj,
    _Float16* __restrict__ scan_out)
{
    const int g = blockIdx.x & 7;
    const int c = (blockIdx.x >> 3) & (NC - 1);
    const int b = blockIdx.x >> 8;
    const int d = g * 256 + threadIdx.x;
    const int row0 = b * L_SZ + c * CL;

    __shared__ float BCs[CL][32];
#pragma unroll
    for (int it = 0; it < (CL * 32) / 256; it++) {
        int i = threadIdx.x + it * 256;
        int l = i >> 5, j = i & 31;
        BCs[l][j] = dbc[(size_t)(row0 + l) * 96 + DTR + j];
    }
    __syncthreads();

    float Aa[NST];
#pragma unroll
    for (int n = 0; n < NST; n++) Aa[n] = -expf(A_log[d * NST + n]);
    const float dtb = dt_b[d];
    const float dsk = D_skip[d];

    float st[NST];
    const size_t ibase = ((size_t)(b * NC + c) * NST) * DIN + d;
#pragma unroll
    for (int n = 0; n < NST; n++) st[n] = I[ibase + (size_t)n * DIN];

    for (int l = 0; l < CL; l++) {
        const size_t row = (size_t)(row0 + l);
        float dtv = softplus_f(dt_lin[row * DIN + d] + dtb);
        float u = ssm_in[row * DIN + d];
        float du = dtv * u;
        float y = 0.f;
#pragma unroll
        for (int n = 0; n < NST; n++) {
            float dA = expf(dtv * Aa[n]);
            st[n] = fmaf(dA, st[n], du * BCs[l][n]);
            y = fmaf(st[n], BCs[l][NST + n], y);
        }
        float gv = proj[row * (2 * DIN) + DIN + d];
        float sg = gv / (1.0f + expf(-gv));
        scan_out[row * DIN + d] = (_Float16)((y + u * dsk) * sg);
    }
}

// ---------------------------------------------------------------------------
extern "C" void kernel_launch(void* const* d_in, const int* in_sizes, int n_in,
                              void* d_out, int out_size, void* d_ws, size_t ws_size,
                              hipStream_t stream) {
    const float* x      = (const float*)d_in[0];
    const int*   mask   = (const int*)d_in[1];
    const float* Wq     = (const float*)d_in[2];
    const float* bq     = (const float*)d_in[3];
    const float* Wk     = (const float*)d_in[4];
    const float* bk     = (const float*)d_in[5];
    const float* Wv     = (const float*)d_in[6];
    const float* bv     = (const float*)d_in[7];
    const float* Wo     = (const float*)d_in[8];
    const float* bo     = (const float*)d_in[9];
    const float* ln_w   = (const float*)d_in[10];
    const float* ln_b   = (const float*)d_in[11];
    const float* mnw    = (const float*)d_in[12];
    const float* in_proj_w = (const float*)d_in[13];
    const float* conv_w = (const float*)d_in[14];
    const float* conv_b = (const float*)d_in[15];
    const float* x_proj_w = (const float*)d_in[16];
    const float* dt_proj_w = (const float*)d_in[17];
    const float* dt_proj_b = (const float*)d_in[18];
    const float* A_log  = (const float*)d_in[19];
    const float* D_skip = (const float*)d_in[20];
    const float* out_proj_w = (const float*)d_in[21];
    const float* fnw    = (const float*)d_in[22];
    float* out = (float*)d_out;
    (void)ws_size; (void)n_in; (void)in_sizes; (void)out_size;

    float* ws = (float*)d_ws;
    const size_t F1 = 1u << 20;
    _Float16* Wqh  = (_Float16*)(ws + 0);
    _Float16* Wkh  = (_Float16*)(ws + F1 / 2);
    _Float16* Wvh  = (_Float16*)(ws + F1);
    _Float16* Woh  = (_Float16*)(ws + F1 * 3 / 2);
    _Float16* inph = (_Float16*)(ws + 2 * F1);
    _Float16* outph= (_Float16*)(ws + 4 * F1);
    _Float16* xprh = (_Float16*)(ws + 5 * F1);              // padded 128x2048
    _Float16* dtph = (_Float16*)(ws + 5 * F1 + F1 / 8);
    _Float16* xh   = (_Float16*)(ws + 5 * F1 + F1 / 4);
    float* x2      = ws + 6 * F1 + F1 / 4;
    float* proj    = ws + 8 * F1 + F1 / 2;                  // 8 F1
    float* q       = proj;
    float* kbuf    = proj + 2 * F1;
    float* vbuf    = proj + 4 * F1;
    float* ctx     = proj + 6 * F1;
    float* x3      = proj;
    _Float16* ctxh = (_Float16*)(ws + 16 * F1 + F1 / 2);
    _Float16* dbch = (_Float16*)(ws + 16 * F1 + F1 / 2);    // reuse (ctxh dead)
    float* dbc     = ws + 16 * F1 + 3 * F1 / 4;
    float* attn_tmp= ws + 17 * F1 + F1 / 2;
    _Float16* ssmh = (_Float16*)attn_tmp;                   // reuse
    float* Pbuf    = attn_tmp;                              // reuse (ssmh dead)
    float* Ibuf    = Pbuf;                                  // alias P (safe)
    _Float16* hh   = (_Float16*)(ws + 19 * F1 + F1 / 2);
    float* ssm     = ws + 20 * F1 + F1 / 2;
    float* dtl     = ws + 24 * F1 + F1 / 2;                 // 4 F1 (used late)
    _Float16* qh16 = (_Float16*)(ws + 24 * F1 + F1 / 2);    // aliases dtl: dead
    _Float16* kh16 = (_Float16*)(ws + 25 * F1 + F1 / 2);    //  before dtl write
    _Float16* vth16= (_Float16*)(ws + 26 * F1 + F1 / 2);
    float* Sbuf    = ws + 28 * F1 + F1 / 2;
    _Float16* sob  = (_Float16*)Sbuf;                       // reuse (S dead)

    const int M = B_SZ * L_SZ;  // 2048
    dim3 blk(256);

    // --- casts ---
    cast_f2h_kernel<<<1024, blk, 0, stream>>>(Wq, Wqh, H_SZ * H_SZ);
    cast_f2h_kernel<<<1024, blk, 0, stream>>>(Wk, Wkh, H_SZ * H_SZ);
    cast_f2h_kernel<<<1024, blk, 0, stream>>>(Wv, Wvh, H_SZ * H_SZ);
    cast_f2h_kernel<<<1024, blk, 0, stream>>>(Wo, Woh, H_SZ * H_SZ);
    cast_f2h_kernel<<<4096, blk, 0, stream>>>(in_proj_w, inph, 2 * DIN * H_SZ);
    cast_f2h_kernel<<<2048, blk, 0, stream>>>(out_proj_w, outph, H_SZ * DIN);
    cast_pad_xproj_kernel<<<1024, blk, 0, stream>>>(x_proj_w, xprh);
    cast_f2h_kernel<<<128, blk, 0, stream>>>(dt_proj_w, dtph, DIN * DTR);
    cast_f2h_kernel<<<2048, blk, 0, stream>>>(x, xh, M * H_SZ);

    // --- QKV ---
    hgemm<<<dim3(8, 16), blk, 0, stream>>>(xh, H_SZ, Wqh, H_SZ, bq, q,    H_SZ, H_SZ, H_SZ);
    hgemm<<<dim3(8, 16), blk, 0, stream>>>(xh, H_SZ, Wkh, H_SZ, bk, kbuf, H_SZ, H_SZ, H_SZ);
    hgemm<<<dim3(8, 16), blk, 0, stream>>>(xh, H_SZ, Wvh, H_SZ, bv, vbuf, H_SZ, H_SZ, H_SZ);

    // --- attention (MFMA flash) ---
    repack_qk_kernel<<<2048, blk, 0, stream>>>(q, kbuf, qh16, kh16);
    vtrans_kernel<<<512, blk, 0, stream>>>(vbuf, vth16);
    attn_mfma<<<512, blk, 0, stream>>>(qh16, kh16, vth16, mask, ctx);
    cast_f2h_kernel<<<2048, blk, 0, stream>>>(ctx, ctxh, M * H_SZ);

    // --- Wo + LN + residual ---
    hgemm<<<dim3(8, 16), blk, 0, stream>>>(ctxh, H_SZ, Woh, H_SZ, bo, attn_tmp, H_SZ, H_SZ, H_SZ);
    add_ln_kernel<<<dim3(M), blk, 0, stream>>>(attn_tmp, x, ln_w, ln_b, x2);

    // --- mamba pre-norm + in_proj ---
    rmsnorm_h_kernel<<<dim3(M), blk, 0, stream>>>(x2, mnw, hh);
    hgemm<<<dim3(32, 16), blk, 0, stream>>>(hh, H_SZ, inph, H_SZ, nullptr, proj, 2 * DIN, 2 * DIN, H_SZ);

    // --- conv + silu ---
    conv_silu_kernel<<<dim3(B_SZ * L_SZ * DIN / 256), blk, 0, stream>>>(proj, mask, conv_w, conv_b, ssm, ssmh);

    // --- x_proj (N=96, padded W) and dt_proj ---
    hgemm<<<dim3(1, 16), blk, 0, stream>>>(ssmh, DIN, xprh, DIN, nullptr, dbc, 96, 96, DIN);
    pack_dbc_kernel<<<512, blk, 0, stream>>>(dbc, dbch);
    hgemm<<<dim3(16, 16), blk, 0, stream>>>(dbch, DTR, dtph, DTR, nullptr, dtl, DIN, DIN, DTR);

    // --- chunked scan ---
    scan_pass1<<<dim3(B_SZ * NC * (DIN / 256)), blk, 0, stream>>>(dtl, dt_proj_b, A_log, dbc, ssm, Pbuf, Sbuf);
    scan_combine<<<dim3(B_SZ * DIN / 256), blk, 0, stream>>>(Pbuf, Sbuf, Ibuf);
    scan_pass2<<<dim3(B_SZ * NC * (DIN / 256)), blk, 0, stream>>>(dtl, dt_proj_b, A_log, dbc, ssm, Ibuf, D_skip, proj, sob);

    // --- out_proj + final norm ---
    hgemm<<<dim3(8, 16), blk, 0, stream>>>(sob, DIN, outph, DIN, nullptr, x3, H_SZ, H_SZ, DIN);
    rmsnorm_kernel<<<dim3(M), blk, 0, stream>>>(x2, x3, fnw, out);
}

// Round 5
// 556.230 us; speedup vs baseline: 7.4900x; 1.2437x over previous
//
#include <hip/hip_runtime.h>
#include <math.h>

#define B_SZ 2
#define L_SZ 1024
#define H_SZ 1024
#define NH_SZ 16
#define HD_SZ 64
#define DIN 2048
#define NST 16
#define KCONV 4
#define DTR 64

#define NC 32   // scan chunks
#define CL 32   // chunk length

typedef _Float16 half8v __attribute__((ext_vector_type(8)));
typedef _Float16 half4v __attribute__((ext_vector_type(4)));
typedef _Float16 half2v __attribute__((ext_vector_type(2)));
typedef float floatx4 __attribute__((ext_vector_type(4)));

// ---------------------------------------------------------------------------
// MFMA f16 GEMM: C[M,N] = A[M,K] @ W[N,K]^T + bias.  M mult of 128, K mult 32.
// ---------------------------------------------------------------------------
__global__ __launch_bounds__(256) void hgemm(
    const _Float16* __restrict__ A, int lda,
    const _Float16* __restrict__ W, int ldw,
    const float* __restrict__ bias,
    float* __restrict__ C, int ldc,
    int N, int K)
{
    __shared__ __align__(16) _Float16 As[128 * 32];
    __shared__ __align__(16) _Float16 Bs[128 * 32];
    const int tid = threadIdx.x;
    const int m0 = blockIdx.y * 128;
    const int n0 = blockIdx.x * 128;
    const int wave = tid >> 6;
    const int lane = tid & 63;
    const int wm = (wave >> 1) * 64;
    const int wn = (wave & 1) * 64;
    const int row_l = tid >> 2;
    const int col_l = (tid & 3) * 8;

    floatx4 zero = {0.f, 0.f, 0.f, 0.f};
    floatx4 acc[4][4];
#pragma unroll
    for (int i = 0; i < 4; i++)
#pragma unroll
        for (int j = 0; j < 4; j++) acc[i][j] = zero;

    const int fr = lane & 15;
    const int fq = (lane >> 4) * 8;

    for (int k0 = 0; k0 < K; k0 += 32) {
        *(half8v*)&As[row_l * 32 + col_l] =
            *(const half8v*)&A[(size_t)(m0 + row_l) * lda + k0 + col_l];
        *(half8v*)&As[(row_l + 64) * 32 + col_l] =
            *(const half8v*)&A[(size_t)(m0 + row_l + 64) * lda + k0 + col_l];
        *(half8v*)&Bs[row_l * 32 + col_l] =
            *(const half8v*)&W[(size_t)(n0 + row_l) * ldw + k0 + col_l];
        *(half8v*)&Bs[(row_l + 64) * 32 + col_l] =
            *(const half8v*)&W[(size_t)(n0 + row_l + 64) * ldw + k0 + col_l];
        __syncthreads();

        half8v af[4], bf[4];
#pragma unroll
        for (int i = 0; i < 4; i++)
            af[i] = *(const half8v*)&As[(wm + i * 16 + fr) * 32 + fq];
#pragma unroll
        for (int j = 0; j < 4; j++)
            bf[j] = *(const half8v*)&Bs[(wn + j * 16 + fr) * 32 + fq];
#pragma unroll
        for (int i = 0; i < 4; i++)
#pragma unroll
            for (int j = 0; j < 4; j++)
                acc[i][j] = __builtin_amdgcn_mfma_f32_16x16x32_f16(
                    af[i], bf[j], acc[i][j], 0, 0, 0);
        __syncthreads();
    }

    const int er = (lane >> 4) * 4;
    const int ec = lane & 15;
#pragma unroll
    for (int j = 0; j < 4; j++) {
        int n = n0 + wn + j * 16 + ec;
        if (n < N) {
            float bv = bias ? bias[n] : 0.f;
#pragma unroll
            for (int i = 0; i < 4; i++) {
#pragma unroll
                for (int r = 0; r < 4; r++) {
                    int m = m0 + wm + i * 16 + er + r;
                    C[(size_t)m * ldc + n] = acc[i][j][r] + bv;
                }
            }
        }
    }
}

// ---------------------------------------------------------------------------
// One combined cast kernel: all weight/input casts in a single launch.
// Segment sizes are compile-time constants (vec4 items).
// ---------------------------------------------------------------------------
#define SEG_QKVW 262144          // 1M f32 each for Wq,Wk,Wv
#define SEG_WO   262144
#define SEG_INP  1048576         // 4M
#define SEG_OUTP 524288          // 2M
#define SEG_DTP  32768           // 128K
#define SEG_X    524288          // 2M
#define SEG_XPR  65536           // 256K dst elems / 4
#define SEG_BQKV 768             // 3072 / 4
#define CAST_TOTAL (SEG_QKVW*3 + SEG_WO + SEG_INP + SEG_OUTP + SEG_DTP + SEG_X + SEG_XPR + SEG_BQKV)

__device__ __forceinline__ void cast4(const float* __restrict__ s,
                                      _Float16* __restrict__ d, int i) {
    float4 v = *(const float4*)&s[i * 4];
    half4v o = {(_Float16)v.x, (_Float16)v.y, (_Float16)v.z, (_Float16)v.w};
    *(half4v*)&d[i * 4] = o;
}

__global__ __launch_bounds__(256) void cast_all(
    const float* __restrict__ Wq, const float* __restrict__ Wk,
    const float* __restrict__ Wv, const float* __restrict__ Wo,
    const float* __restrict__ inp, const float* __restrict__ outp,
    const float* __restrict__ dtp, const float* __restrict__ x,
    const float* __restrict__ xpr,
    const float* __restrict__ bq, const float* __restrict__ bk,
    const float* __restrict__ bv,
    _Float16* __restrict__ Wqkvh, _Float16* __restrict__ Woh,
    _Float16* __restrict__ inph, _Float16* __restrict__ outph,
    _Float16* __restrict__ dtph, _Float16* __restrict__ xh,
    _Float16* __restrict__ xprh, float* __restrict__ bqkv)
{
    int i = blockIdx.x * 256 + threadIdx.x;
    if (i < SEG_QKVW) { cast4(Wq, Wqkvh, i); return; }
    i -= SEG_QKVW;
    if (i < SEG_QKVW) { cast4(Wk, Wqkvh + H_SZ * H_SZ, i); return; }
    i -= SEG_QKVW;
    if (i < SEG_QKVW) { cast4(Wv, Wqkvh + 2 * H_SZ * H_SZ, i); return; }
    i -= SEG_QKVW;
    if (i < SEG_WO)   { cast4(Wo, Woh, i); return; }
    i -= SEG_WO;
    if (i < SEG_INP)  { cast4(inp, inph, i); return; }
    i -= SEG_INP;
    if (i < SEG_OUTP) { cast4(outp, outph, i); return; }
    i -= SEG_OUTP;
    if (i < SEG_DTP)  { cast4(dtp, dtph, i); return; }
    i -= SEG_DTP;
    if (i < SEG_X)    { cast4(x, xh, i); return; }
    i -= SEG_X;
    if (i < SEG_XPR) {
        int e = i * 4;
        int r = e >> 11;
        if (r < 96) {
            cast4(xpr, xprh, i);
        } else {
            half4v z = {(_Float16)0.f, (_Float16)0.f, (_Float16)0.f, (_Float16)0.f};
            *(half4v*)&xprh[e] = z;
        }
        return;
    }
    i -= SEG_XPR;
    if (i < SEG_BQKV) {
        int e = i * 4;
        const float* src = (e < 1024) ? (bq + e) : (e < 2048) ? (bk + e - 1024) : (bv + e - 2048);
        *(float4*)&bqkv[e] = *(const float4*)src;
    }
}

// pack dbc[:, :64] (stride 96) -> [2048,64] f16
__global__ __launch_bounds__(256) void pack_dbc_kernel(
    const float* __restrict__ s, _Float16* __restrict__ d)
{
    int i = blockIdx.x * 256 + threadIdx.x;   // 2048*64
    int r = i >> 6, c = i & 63;
    d[i] = (_Float16)s[r * 96 + c];
}

// ---------------------------------------------------------------------------
// qkv f32 [b][l][3072] -> qh,kh f16 [b][h][l][hd], vth f16 [b][h][hd][l]
// block = (b, h, 64-row l tile), 256 threads
// ---------------------------------------------------------------------------
__global__ __launch_bounds__(256) void repack_attn(
    const float* __restrict__ qkv,
    _Float16* __restrict__ qh, _Float16* __restrict__ kh,
    _Float16* __restrict__ vth)
{
    const int lt = blockIdx.x & 15;
    const int h  = (blockIdx.x >> 4) & (NH_SZ - 1);
    const int b  = blockIdx.x >> 8;
    const int tid = threadIdx.x;
    const int r  = tid >> 2;          // 0..63 (l within tile)
    const int c0 = (tid & 3) * 16;    // 16 cols per thread

    const size_t srcrow = (size_t)(b * L_SZ + lt * 64 + r) * 3072 + h * 64;
    _Float16* qdst = qh + ((size_t)(b * NH_SZ + h) * L_SZ + lt * 64 + r) * HD_SZ;
    _Float16* kdst = kh + ((size_t)(b * NH_SZ + h) * L_SZ + lt * 64 + r) * HD_SZ;

    __shared__ float Vf[64 * 65];
#pragma unroll
    for (int u = 0; u < 4; u++) {
        int c = c0 + u * 4;
        float4 vq = *(const float4*)&qkv[srcrow + c];
        float4 vk = *(const float4*)&qkv[srcrow + 1024 + c];
        float4 vv = *(const float4*)&qkv[srcrow + 2048 + c];
        half4v oq = {(_Float16)vq.x, (_Float16)vq.y, (_Float16)vq.z, (_Float16)vq.w};
        half4v ok = {(_Float16)vk.x, (_Float16)vk.y, (_Float16)vk.z, (_Float16)vk.w};
        *(half4v*)&qdst[c] = oq;
        *(half4v*)&kdst[c] = ok;
        Vf[r * 65 + c + 0] = vv.x;
        Vf[r * 65 + c + 1] = vv.y;
        Vf[r * 65 + c + 2] = vv.z;
        Vf[r * 65 + c + 3] = vv.w;
    }
    __syncthreads();
    const int hd = tid >> 2;
    const int l0 = (tid & 3) * 16;
    _Float16* dst = vth + ((size_t)(b * NH_SZ + h) * HD_SZ + hd) * L_SZ + lt * 64 + l0;
#pragma unroll
    for (int kk = 0; kk < 16; kk += 2) {
        half2v o = {(_Float16)Vf[(l0 + kk) * 65 + hd],
                    (_Float16)Vf[(l0 + kk + 1) * 65 + hd]};
        *(half2v*)&dst[kk] = o;
    }
}

// ---------------------------------------------------------------------------
// MFMA flash attention: block = (b, h, 64-row q tile); 4 waves x 16 q rows.
// Writes ctx directly in f16.
// ---------------------------------------------------------------------------
__global__ __launch_bounds__(256) void attn_mfma(
    const _Float16* __restrict__ qh, const _Float16* __restrict__ kh,
    const _Float16* __restrict__ vth, const int* __restrict__ mask,
    _Float16* __restrict__ ctxh)
{
    const int qt = blockIdx.x & 15;
    const int h  = (blockIdx.x >> 4) & (NH_SZ - 1);
    const int b  = blockIdx.x >> 8;
    const int tid = threadIdx.x;
    const int wave = tid >> 6;
    const int lane = tid & 63;
    const int fr = lane & 15;
    const int g  = lane >> 4;
    const int fq = g * 8;
    const int g4 = g * 4;

    __shared__ __align__(16) _Float16 Qs[64 * 72];
    __shared__ __align__(16) _Float16 Ks[64 * 72];
    __shared__ __align__(16) _Float16 Vs[64 * 72];
    __shared__ __align__(16) _Float16 Ps[4][16 * 72];

    const _Float16* qbase = qh + ((size_t)(b * NH_SZ + h) * L_SZ + qt * 64) * HD_SZ;
    const _Float16* kbase = kh + (size_t)(b * NH_SZ + h) * L_SZ * HD_SZ;
    const _Float16* vbase = vth + (size_t)(b * NH_SZ + h) * HD_SZ * L_SZ;

#pragma unroll
    for (int p = 0; p < 2; p++) {
        int lin = p * 2048 + tid * 8;
        int r = lin >> 6, c = lin & 63;
        *(half8v*)&Qs[r * 72 + c] = *(const half8v*)&qbase[r * 64 + c];
    }
    __syncthreads();
    half8v aQ[2];
    aQ[0] = *(const half8v*)&Qs[(wave * 16 + fr) * 72 + 0 + fq];
    aQ[1] = *(const half8v*)&Qs[(wave * 16 + fr) * 72 + 32 + fq];

    float m_run[4] = {-1e30f, -1e30f, -1e30f, -1e30f};
    float l_run[4] = {0.f, 0.f, 0.f, 0.f};
    floatx4 zero = {0.f, 0.f, 0.f, 0.f};
    floatx4 accO[4];
#pragma unroll
    for (int jn = 0; jn < 4; jn++) accO[jn] = zero;

    for (int kb = 0; kb < L_SZ / 64; kb++) {
        __syncthreads();
#pragma unroll
        for (int p = 0; p < 2; p++) {
            int lin = p * 2048 + tid * 8;
            int r = lin >> 6, c = lin & 63;
            *(half8v*)&Ks[r * 72 + c] = *(const half8v*)&kbase[(kb * 64 + r) * 64 + c];
            *(half8v*)&Vs[r * 72 + c] = *(const half8v*)&vbase[(size_t)r * L_SZ + kb * 64 + c];
        }
        __syncthreads();

        floatx4 sc[4];
#pragma unroll
        for (int jn = 0; jn < 4; jn++) {
            half8v bk0 = *(const half8v*)&Ks[(jn * 16 + fr) * 72 + 0 + fq];
            half8v bk1 = *(const half8v*)&Ks[(jn * 16 + fr) * 72 + 32 + fq];
            floatx4 t = __builtin_amdgcn_mfma_f32_16x16x32_f16(aQ[0], bk0, zero, 0, 0, 0);
            sc[jn] = __builtin_amdgcn_mfma_f32_16x16x32_f16(aQ[1], bk1, t, 0, 0, 0);
        }

        float s[4][4], p[4][4];
#pragma unroll
        for (int jn = 0; jn < 4; jn++) {
            float ml = (float)mask[b * L_SZ + kb * 64 + jn * 16 + fr];
#pragma unroll
            for (int r = 0; r < 4; r++) s[jn][r] = sc[jn][r] * 0.125f + ml;
        }
#pragma unroll
        for (int r = 0; r < 4; r++) {
            float tm = fmaxf(fmaxf(s[0][r], s[1][r]), fmaxf(s[2][r], s[3][r]));
#pragma unroll
            for (int off = 1; off < 16; off <<= 1) tm = fmaxf(tm, __shfl_xor(tm, off));
            float mn = fmaxf(m_run[r], tm);
            float alpha = expf(m_run[r] - mn);
            float rs = 0.f;
#pragma unroll
            for (int jn = 0; jn < 4; jn++) {
                float pv = expf(s[jn][r] - mn);
                p[jn][r] = pv;
                rs += pv;
            }
#pragma unroll
            for (int off = 1; off < 16; off <<= 1) rs += __shfl_xor(rs, off);
            l_run[r] = l_run[r] * alpha + rs;
            m_run[r] = mn;
#pragma unroll
            for (int jn = 0; jn < 4; jn++) accO[jn][r] *= alpha;
        }
#pragma unroll
        for (int jn = 0; jn < 4; jn++)
#pragma unroll
            for (int r = 0; r < 4; r++)
                Ps[wave][(g4 + r) * 72 + jn * 16 + fr] = (_Float16)p[jn][r];
        __syncthreads();

        half8v aP0 = *(const half8v*)&Ps[wave][fr * 72 + 0 + fq];
        half8v aP1 = *(const half8v*)&Ps[wave][fr * 72 + 32 + fq];
#pragma unroll
        for (int jn = 0; jn < 4; jn++) {
            half8v bv0 = *(const half8v*)&Vs[(jn * 16 + fr) * 72 + 0 + fq];
            half8v bv1 = *(const half8v*)&Vs[(jn * 16 + fr) * 72 + 32 + fq];
            accO[jn] = __builtin_amdgcn_mfma_f32_16x16x32_f16(aP0, bv0, accO[jn], 0, 0, 0);
            accO[jn] = __builtin_amdgcn_mfma_f32_16x16x32_f16(aP1, bv1, accO[jn], 0, 0, 0);
        }
    }

#pragma unroll
    for (int jn = 0; jn < 4; jn++) {
#pragma unroll
        for (int r = 0; r < 4; r++) {
            int qrow = qt * 64 + wave * 16 + g4 + r;
            ctxh[((size_t)(b * L_SZ) + qrow) * H_SZ + h * 64 + jn * 16 + fr] =
                (_Float16)(accO[jn][r] / l_run[r]);
        }
    }
}

// ---------------------------------------------------------------------------
__device__ __forceinline__ float block_sum256(float v) {
    __shared__ float red[4];
#pragma unroll
    for (int off = 32; off; off >>= 1) v += __shfl_down(v, off);
    __syncthreads();
    if ((threadIdx.x & 63) == 0) red[threadIdx.x >> 6] = v;
    __syncthreads();
    return red[0] + red[1] + red[2] + red[3];
}

__global__ __launch_bounds__(256) void add_ln_kernel(
    const float* __restrict__ t_in, const float* __restrict__ x_in,
    const float* __restrict__ w, const float* __restrict__ bparm,
    float* __restrict__ out)
{
    const int row = blockIdx.x;
    const int c0 = threadIdx.x * 4;
    float4 tv = *(const float4*)(t_in + (size_t)row * H_SZ + c0);
    float4 xv = *(const float4*)(x_in + (size_t)row * H_SZ + c0);
    float vals[4] = {tv.x + xv.x, tv.y + xv.y, tv.z + xv.z, tv.w + xv.w};
    float xr[4] = {xv.x, xv.y, xv.z, xv.w};
    float s = vals[0] + vals[1] + vals[2] + vals[3];
    float mu = block_sum256(s) * (1.0f / H_SZ);
    float vs = 0.f;
#pragma unroll
    for (int i = 0; i < 4; i++) {
        float d = vals[i] - mu;
        vs += d * d;
    }
    float var = block_sum256(vs) * (1.0f / H_SZ);
    float inv = rsqrtf(var + 1e-12f);
#pragma unroll
    for (int i = 0; i < 4; i++) {
        int c = c0 + i;
        out[(size_t)row * H_SZ + c] =
            (vals[i] - mu) * inv * w[c] + bparm[c] + xr[i];
    }
}

__global__ __launch_bounds__(256) void rmsnorm_h_kernel(
    const float* __restrict__ x, const float* __restrict__ w,
    _Float16* __restrict__ out)
{
    const int row = blockIdx.x;
    const int c0 = threadIdx.x * 4;
    float4 xv = *(const float4*)(x + (size_t)row * H_SZ + c0);
    float vals[4] = {xv.x, xv.y, xv.z, xv.w};
    float s = vals[0]*vals[0] + vals[1]*vals[1] + vals[2]*vals[2] + vals[3]*vals[3];
    float ms = block_sum256(s) * (1.0f / H_SZ);
    float inv = rsqrtf(ms + 1e-6f);
    half4v o;
#pragma unroll
    for (int i = 0; i < 4; i++) o[i] = (_Float16)(vals[i] * inv * w[c0 + i]);
    *(half4v*)&out[(size_t)row * H_SZ + c0] = o;
}

__global__ __launch_bounds__(256) void rmsnorm_kernel(
    const float* __restrict__ x, const float* __restrict__ add,
    const float* __restrict__ w, float* __restrict__ out)
{
    const int row = blockIdx.x;
    const int c0 = threadIdx.x * 4;
    float4 xv = *(const float4*)(x + (size_t)row * H_SZ + c0);
    float vals[4] = {xv.x, xv.y, xv.z, xv.w};
    if (add) {
        float4 av = *(const float4*)(add + (size_t)row * H_SZ + c0);
        vals[0] += av.x; vals[1] += av.y; vals[2] += av.z; vals[3] += av.w;
    }
    float s = vals[0]*vals[0] + vals[1]*vals[1] + vals[2]*vals[2] + vals[3]*vals[3];
    float ms = block_sum256(s) * (1.0f / H_SZ);
    float inv = rsqrtf(ms + 1e-6f);
#pragma unroll
    for (int i = 0; i < 4; i++) {
        int c = c0 + i;
        out[(size_t)row * H_SZ + c] = vals[i] * inv * w[c];
    }
}

__global__ __launch_bounds__(256) void conv_silu_kernel(
    const float* __restrict__ proj, const int* __restrict__ mask,
    const float* __restrict__ conv_w, const float* __restrict__ conv_b,
    float* __restrict__ ssm_f, _Float16* __restrict__ ssm_h)
{
    const int idx = blockIdx.x * 256 + threadIdx.x;  // b*L*DIN + l*DIN + d
    const int d = idx & (DIN - 1);
    const int l = (idx >> 11) & (L_SZ - 1);
    const int b = idx >> 21;
    float acc = conv_b[d];
#pragma unroll
    for (int j = 0; j < KCONV; j++) {
        int lp = l - (KCONV - 1) + j;
        if (lp >= 0) {
            float hv = proj[(size_t)(b * L_SZ + lp) * (2 * DIN) + d] *
                       (float)mask[b * L_SZ + lp];
            acc = fmaf(hv, conv_w[d * KCONV + j], acc);
        }
    }
    float sg = 1.0f / (1.0f + expf(-acc));
    float r = acc * sg * (float)mask[b * L_SZ + l];
    ssm_f[idx] = r;
    ssm_h[idx] = (_Float16)r;
}

// ---------------------------------------------------------------------------
// Chunked selective scan
// ---------------------------------------------------------------------------
__device__ __forceinline__ float softplus_f(float x) {
    return (x > 20.f) ? x : log1pf(expf(x));
}

__global__ __launch_bounds__(256) void scan_pass1(
    const float* __restrict__ dt_lin, const float* __restrict__ dt_b,
    const float* __restrict__ A_log, const float* __restrict__ dbc,
    const float* __restrict__ ssm_in,
    float* __restrict__ P, float* __restrict__ S)
{
    const int g = blockIdx.x & 7;
    const int c = (blockIdx.x >> 3) & (NC - 1);
    const int b = blockIdx.x >> 8;
    const int d = g * 256 + threadIdx.x;
    const int row0 = b * L_SZ + c * CL;

    __shared__ float BCs[CL][32];
#pragma unroll
    for (int it = 0; it < (CL * 32) / 256; it++) {
        int i = threadIdx.x + it * 256;
        int l = i >> 5, j = i & 31;
        BCs[l][j] = dbc[(size_t)(row0 + l) * 96 + DTR + j];
    }
    __syncthreads();

    float Aa[NST];
#pragma unroll
    for (int n = 0; n < NST; n++) Aa[n] = -expf(A_log[d * NST + n]);
    const float dtb = dt_b[d];

    float st[NST] = {};
    float Pv[NST];
#pragma unroll
    for (int n = 0; n < NST; n++) Pv[n] = 1.0f;

    for (int l = 0; l < CL; l++) {
        const size_t row = (size_t)(row0 + l);
        float dtv = softplus_f(dt_lin[row * DIN + d] + dtb);
        float u = ssm_in[row * DIN + d];
        float du = dtv * u;
#pragma unroll
        for (int n = 0; n < NST; n++) {
            float dA = expf(dtv * Aa[n]);
            st[n] = fmaf(dA, st[n], du * BCs[l][n]);
            Pv[n] *= dA;
        }
    }
    const size_t base = ((size_t)(b * NC + c) * NST) * DIN + d;
#pragma unroll
    for (int n = 0; n < NST; n++) {
        P[base + (size_t)n * DIN] = Pv[n];
        S[base + (size_t)n * DIN] = st[n];
    }
}

// parallel over (b, n, d): 256 blocks
__global__ __launch_bounds__(256) void scan_combine(
    const float* __restrict__ P, const float* __restrict__ S,
    float* __restrict__ I)
{
    const int idx = blockIdx.x * 256 + threadIdx.x;  // b*NST*DIN + n*DIN + d
    const int d = idx & (DIN - 1);
    const int n = (idx >> 11) & (NST - 1);
    const int b = idx >> 15;
    float st = 0.f;
#pragma unroll 4
    for (int c = 0; c < NC; c++) {
        const size_t o = ((size_t)((b * NC + c) * NST) + n) * DIN + d;
        float pv = P[o], sv = S[o];
        I[o] = st;
        st = fmaf(pv, st, sv);
    }
}

__global__ __launch_bounds__(256) void scan_pass2(
    const float* __restrict__ dt_lin, const float* __restrict__ dt_b,
    const float* __restrict__ A_log, const float* __restrict__ dbc,
    const float* __restrict__ ssm_in, const float* __restrict__ I,
    const float* __restrict__ D_skip, const float* __restrict__ proj,
    _Float16* __restrict__ scan_out)
{
    const int g = blockIdx.x & 7;
    const int c = (blockIdx.x >> 3) & (NC - 1);
    const int b = blockIdx.x >> 8;
    const int d = g * 256 + threadIdx.x;
    const int row0 = b * L_SZ + c * CL;

    __shared__ float BCs[CL][32];
#pragma unroll
    for (int it = 0; it < (CL * 32) / 256; it++) {
        int i = threadIdx.x + it * 256;
        int l = i >> 5, j = i & 31;
        BCs[l][j] = dbc[(size_t)(row0 + l) * 96 + DTR + j];
    }
    __syncthreads();

    float Aa[NST];
#pragma unroll
    for (int n = 0; n < NST; n++) Aa[n] = -expf(A_log[d * NST + n]);
    const float dtb = dt_b[d];
    const float dsk = D_skip[d];

    float st[NST];
    const size_t ibase = ((size_t)(b * NC + c) * NST) * DIN + d;
#pragma unroll
    for (int n = 0; n < NST; n++) st[n] = I[ibase + (size_t)n * DIN];

    for (int l = 0; l < CL; l++) {
        const size_t row = (size_t)(row0 + l);
        float dtv = softplus_f(dt_lin[row * DIN + d] + dtb);
        float u = ssm_in[row * DIN + d];
        float du = dtv * u;
        float y = 0.f;
#pragma unroll
        for (int n = 0; n < NST; n++) {
            float dA = expf(dtv * Aa[n]);
            st[n] = fmaf(dA, st[n], du * BCs[l][n]);
            y = fmaf(st[n], BCs[l][NST + n], y);
        }
        float gv = proj[row * (2 * DIN) + DIN + d];
        float sg = gv / (1.0f + expf(-gv));
        scan_out[row * DIN + d] = (_Float16)((y + u * dsk) * sg);
    }
}

// ---------------------------------------------------------------------------
extern "C" void kernel_launch(void* const* d_in, const int* in_sizes, int n_in,
                              void* d_out, int out_size, void* d_ws, size_t ws_size,
                              hipStream_t stream) {
    const float* x      = (const float*)d_in[0];
    const int*   mask   = (const int*)d_in[1];
    const float* Wq     = (const float*)d_in[2];
    const float* bq     = (const float*)d_in[3];
    const float* Wk     = (const float*)d_in[4];
    const float* bk     = (const float*)d_in[5];
    const float* Wv     = (const float*)d_in[6];
    const float* bv     = (const float*)d_in[7];
    const float* Wo     = (const float*)d_in[8];
    const float* bo     = (const float*)d_in[9];
    const float* ln_w   = (const float*)d_in[10];
    const float* ln_b   = (const float*)d_in[11];
    const float* mnw    = (const float*)d_in[12];
    const float* in_proj_w = (const float*)d_in[13];
    const float* conv_w = (const float*)d_in[14];
    const float* conv_b = (const float*)d_in[15];
    const float* x_proj_w = (const float*)d_in[16];
    const float* dt_proj_w = (const float*)d_in[17];
    const float* dt_proj_b = (const float*)d_in[18];
    const float* A_log  = (const float*)d_in[19];
    const float* D_skip = (const float*)d_in[20];
    const float* out_proj_w = (const float*)d_in[21];
    const float* fnw    = (const float*)d_in[22];
    float* out = (float*)d_out;
    (void)ws_size; (void)n_in; (void)in_sizes; (void)out_size;

    float* ws = (float*)d_ws;
    const size_t F1 = 1u << 20;
    _Float16* Wqkvh = (_Float16*)(ws + 0);                  // [0, 1.5F)
    _Float16* Woh  = (_Float16*)(ws + 3 * F1 / 2);          // [1.5F, 2F)
    _Float16* inph = (_Float16*)(ws + 2 * F1);              // [2F, 4F)
    _Float16* outph= (_Float16*)(ws + 4 * F1);              // [4F, 5F)
    _Float16* xprh = (_Float16*)(ws + 5 * F1);              // [5F, 5.125F)
    _Float16* dtph = (_Float16*)(ws + 5 * F1 + F1 / 8);     // [5.125F, 5.1875F)
    float* bqkv    = ws + 5 * F1 + 3 * F1 / 16;             // [5.1875F, 5.25F)
    _Float16* xh   = (_Float16*)(ws + 5 * F1 + F1 / 4);     // [5.25F, 6.25F)
    float* x2      = ws + 6 * F1 + F1 / 4;                  // [6.25F, 8.25F)
    float* proj    = ws + 8 * F1 + F1 / 2;                  // [8.5F, 16.5F)
    float* qkv     = proj;                                  // [8.5F, 14.5F) dead before proj
    float* x3      = proj;                                  // after pass2
    _Float16* ctxh = (_Float16*)(ws + 16 * F1 + F1 / 2);    // [16.5F, 17.5F)
    _Float16* dbch = (_Float16*)(ws + 16 * F1 + F1 / 2);    // reuse (ctxh dead)
    float* dbc     = ws + 16 * F1 + 3 * F1 / 4;             // [16.75F, 16.94F)
    float* attn_tmp= ws + 17 * F1 + F1 / 2;                 // [17.5F, 19.5F)
    _Float16* ssmh = (_Float16*)attn_tmp;                   // reuse
    float* Pbuf    = attn_tmp;                              // reuse (ssmh dead)
    float* Ibuf    = Pbuf;                                  // alias P (safe)
    _Float16* hh   = (_Float16*)(ws + 19 * F1 + F1 / 2);    // [19.5F, 20.5F)
    float* ssm     = ws + 20 * F1 + F1 / 2;                 // [20.5F, 24.5F)
    float* dtl     = ws + 24 * F1 + F1 / 2;                 // [24.5F, 28.5F)
    _Float16* qh16 = (_Float16*)(ws + 24 * F1 + F1 / 2);    // alias dtl (dead before)
    _Float16* kh16 = (_Float16*)(ws + 25 * F1 + F1 / 2);
    _Float16* vth16= (_Float16*)(ws + 26 * F1 + F1 / 2);
    float* Sbuf    = ws + 28 * F1 + F1 / 2;                 // [28.5F, 30.5F)
    _Float16* sob  = (_Float16*)Sbuf;                       // reuse (S dead)

    const int M = B_SZ * L_SZ;  // 2048
    dim3 blk(256);

    // --- all casts, one launch ---
    cast_all<<<dim3(CAST_TOTAL / 256), blk, 0, stream>>>(
        Wq, Wk, Wv, Wo, in_proj_w, out_proj_w, dt_proj_w, x, x_proj_w,
        bq, bk, bv, Wqkvh, Woh, inph, outph, dtph, xh, xprh, bqkv);

    // --- fused QKV GEMM ---
    hgemm<<<dim3(24, 16), blk, 0, stream>>>(xh, H_SZ, Wqkvh, H_SZ, bqkv, qkv, 3 * H_SZ, 3 * H_SZ, H_SZ);

    // --- attention (repack + MFMA flash, f16 ctx out) ---
    repack_attn<<<512, blk, 0, stream>>>(qkv, qh16, kh16, vth16);
    attn_mfma<<<512, blk, 0, stream>>>(qh16, kh16, vth16, mask, ctxh);

    // --- Wo + LN + residual ---
    hgemm<<<dim3(8, 16), blk, 0, stream>>>(ctxh, H_SZ, Woh, H_SZ, bo, attn_tmp, H_SZ, H_SZ, H_SZ);
    add_ln_kernel<<<dim3(M), blk, 0, stream>>>(attn_tmp, x, ln_w, ln_b, x2);

    // --- mamba pre-norm + in_proj ---
    rmsnorm_h_kernel<<<dim3(M), blk, 0, stream>>>(x2, mnw, hh);
    hgemm<<<dim3(32, 16), blk, 0, stream>>>(hh, H_SZ, inph, H_SZ, nullptr, proj, 2 * DIN, 2 * DIN, H_SZ);

    // --- conv + silu ---
    conv_silu_kernel<<<dim3(B_SZ * L_SZ * DIN / 256), blk, 0, stream>>>(proj, mask, conv_w, conv_b, ssm, ssmh);

    // --- x_proj (N=96, padded W) and dt_proj ---
    hgemm<<<dim3(1, 16), blk, 0, stream>>>(ssmh, DIN, xprh, DIN, nullptr, dbc, 96, 96, DIN);
    pack_dbc_kernel<<<512, blk, 0, stream>>>(dbc, dbch);
    hgemm<<<dim3(16, 16), blk, 0, stream>>>(dbch, DTR, dtph, DTR, nullptr, dtl, DIN, DIN, DTR);

    // --- chunked scan ---
    scan_pass1<<<dim3(B_SZ * NC * (DIN / 256)), blk, 0, stream>>>(dtl, dt_proj_b, A_log, dbc, ssm, Pbuf, Sbuf);
    scan_combine<<<dim3(B_SZ * NST * DIN / 256), blk, 0, stream>>>(Pbuf, Sbuf, Ibuf);
    scan_pass2<<<dim3(B_SZ * NC * (DIN / 256)), blk, 0, stream>>>(dtl, dt_proj_b, A_log, dbc, ssm, Ibuf, D_skip, proj, sob);

    // --- out_proj + final norm ---
    hgemm<<<dim3(8, 16), blk, 0, stream>>>(sob, DIN, outph, DIN, nullptr, x3, H_SZ, H_SZ, DIN);
    rmsnorm_kernel<<<dim3(M), blk, 0, stream>>>(x2, x3, fnw, out);
}

// Round 6
// 485.860 us; speedup vs baseline: 8.5748x; 1.1448x over previous
//
#include <hip/hip_runtime.h>
#include <math.h>

#define B_SZ 2
#define L_SZ 1024
#define H_SZ 1024
#define NH_SZ 16
#define HD_SZ 64
#define DIN 2048
#define NST 16
#define KCONV 4
#define DTR 64

#define NC 32   // scan chunks
#define CL 32   // chunk length

#define L2E 1.4426950408889634f
#define LN2 0.6931471805599453f

typedef _Float16 half8v __attribute__((ext_vector_type(8)));
typedef _Float16 half4v __attribute__((ext_vector_type(4)));
typedef _Float16 half2v __attribute__((ext_vector_type(2)));
typedef float floatx4 __attribute__((ext_vector_type(4)));

__device__ __forceinline__ float exp_fast(float x) {
    return __builtin_amdgcn_exp2f(x * L2E);
}
__device__ __forceinline__ float softplus_f(float x) {
    if (x > 20.f) return x;
    float e = __builtin_amdgcn_exp2f(x * L2E);
    return LN2 * __builtin_amdgcn_logf(1.0f + e);
}
__device__ __forceinline__ float sigmoid_fast(float x) {
    return __builtin_amdgcn_rcpf(1.0f + __builtin_amdgcn_exp2f(-x * L2E));
}

// ---------------------------------------------------------------------------
// MFMA f16 GEMM: C[M,N] = A[M,K] @ W[N,K]^T + bias.  M mult of 128, K mult 32.
// ---------------------------------------------------------------------------
__global__ __launch_bounds__(256) void hgemm(
    const _Float16* __restrict__ A, int lda,
    const _Float16* __restrict__ W, int ldw,
    const float* __restrict__ bias,
    float* __restrict__ C, int ldc,
    int N, int K)
{
    __shared__ __align__(16) _Float16 As[128 * 32];
    __shared__ __align__(16) _Float16 Bs[128 * 32];
    const int tid = threadIdx.x;
    const int m0 = blockIdx.y * 128;
    const int n0 = blockIdx.x * 128;
    const int wave = tid >> 6;
    const int lane = tid & 63;
    const int wm = (wave >> 1) * 64;
    const int wn = (wave & 1) * 64;
    const int row_l = tid >> 2;
    const int col_l = (tid & 3) * 8;

    floatx4 zero = {0.f, 0.f, 0.f, 0.f};
    floatx4 acc[4][4];
#pragma unroll
    for (int i = 0; i < 4; i++)
#pragma unroll
        for (int j = 0; j < 4; j++) acc[i][j] = zero;

    const int fr = lane & 15;
    const int fq = (lane >> 4) * 8;

    for (int k0 = 0; k0 < K; k0 += 32) {
        *(half8v*)&As[row_l * 32 + col_l] =
            *(const half8v*)&A[(size_t)(m0 + row_l) * lda + k0 + col_l];
        *(half8v*)&As[(row_l + 64) * 32 + col_l] =
            *(const half8v*)&A[(size_t)(m0 + row_l + 64) * lda + k0 + col_l];
        *(half8v*)&Bs[row_l * 32 + col_l] =
            *(const half8v*)&W[(size_t)(n0 + row_l) * ldw + k0 + col_l];
        *(half8v*)&Bs[(row_l + 64) * 32 + col_l] =
            *(const half8v*)&W[(size_t)(n0 + row_l + 64) * ldw + k0 + col_l];
        __syncthreads();

        half8v af[4], bf[4];
#pragma unroll
        for (int i = 0; i < 4; i++)
            af[i] = *(const half8v*)&As[(wm + i * 16 + fr) * 32 + fq];
#pragma unroll
        for (int j = 0; j < 4; j++)
            bf[j] = *(const half8v*)&Bs[(wn + j * 16 + fr) * 32 + fq];
#pragma unroll
        for (int i = 0; i < 4; i++)
#pragma unroll
            for (int j = 0; j < 4; j++)
                acc[i][j] = __builtin_amdgcn_mfma_f32_16x16x32_f16(
                    af[i], bf[j], acc[i][j], 0, 0, 0);
        __syncthreads();
    }

    const int er = (lane >> 4) * 4;
    const int ec = lane & 15;
#pragma unroll
    for (int j = 0; j < 4; j++) {
        int n = n0 + wn + j * 16 + ec;
        if (n < N) {
            float bv = bias ? bias[n] : 0.f;
#pragma unroll
            for (int i = 0; i < 4; i++) {
#pragma unroll
                for (int r = 0; r < 4; r++) {
                    int m = m0 + wm + i * 16 + er + r;
                    C[(size_t)m * ldc + n] = acc[i][j][r] + bv;
                }
            }
        }
    }
}

// ---------------------------------------------------------------------------
// One combined cast kernel (vec4 items per segment)
// ---------------------------------------------------------------------------
#define SEG_QKVW 262144
#define SEG_WO   262144
#define SEG_INP  1048576
#define SEG_OUTP 524288
#define SEG_DTP  32768
#define SEG_X    524288
#define SEG_XPR  65536
#define SEG_BQKV 768
#define CAST_TOTAL (SEG_QKVW*3 + SEG_WO + SEG_INP + SEG_OUTP + SEG_DTP + SEG_X + SEG_XPR + SEG_BQKV)

__device__ __forceinline__ void cast4(const float* __restrict__ s,
                                      _Float16* __restrict__ d, int i) {
    float4 v = *(const float4*)&s[i * 4];
    half4v o = {(_Float16)v.x, (_Float16)v.y, (_Float16)v.z, (_Float16)v.w};
    *(half4v*)&d[i * 4] = o;
}

__global__ __launch_bounds__(256) void cast_all(
    const float* __restrict__ Wq, const float* __restrict__ Wk,
    const float* __restrict__ Wv, const float* __restrict__ Wo,
    const float* __restrict__ inp, const float* __restrict__ outp,
    const float* __restrict__ dtp, const float* __restrict__ x,
    const float* __restrict__ xpr,
    const float* __restrict__ bq, const float* __restrict__ bk,
    const float* __restrict__ bv,
    _Float16* __restrict__ Wqkvh, _Float16* __restrict__ Woh,
    _Float16* __restrict__ inph, _Float16* __restrict__ outph,
    _Float16* __restrict__ dtph, _Float16* __restrict__ xh,
    _Float16* __restrict__ xprh, float* __restrict__ bqkv)
{
    int i = blockIdx.x * 256 + threadIdx.x;
    if (i < SEG_QKVW) { cast4(Wq, Wqkvh, i); return; }
    i -= SEG_QKVW;
    if (i < SEG_QKVW) { cast4(Wk, Wqkvh + H_SZ * H_SZ, i); return; }
    i -= SEG_QKVW;
    if (i < SEG_QKVW) { cast4(Wv, Wqkvh + 2 * H_SZ * H_SZ, i); return; }
    i -= SEG_QKVW;
    if (i < SEG_WO)   { cast4(Wo, Woh, i); return; }
    i -= SEG_WO;
    if (i < SEG_INP)  { cast4(inp, inph, i); return; }
    i -= SEG_INP;
    if (i < SEG_OUTP) { cast4(outp, outph, i); return; }
    i -= SEG_OUTP;
    if (i < SEG_DTP)  { cast4(dtp, dtph, i); return; }
    i -= SEG_DTP;
    if (i < SEG_X)    { cast4(x, xh, i); return; }
    i -= SEG_X;
    if (i < SEG_XPR) {
        int e = i * 4;
        int r = e >> 11;
        if (r < 96) {
            cast4(xpr, xprh, i);
        } else {
            half4v z = {(_Float16)0.f, (_Float16)0.f, (_Float16)0.f, (_Float16)0.f};
            *(half4v*)&xprh[e] = z;
        }
        return;
    }
    i -= SEG_XPR;
    if (i < SEG_BQKV) {
        int e = i * 4;
        const float* src = (e < 1024) ? (bq + e) : (e < 2048) ? (bk + e - 1024) : (bv + e - 2048);
        *(float4*)&bqkv[e] = *(const float4*)src;
    }
}

// pack dbc[:, :64] (stride 96) -> [2048,64] f16
__global__ __launch_bounds__(256) void pack_dbc_kernel(
    const float* __restrict__ s, _Float16* __restrict__ d)
{
    int i = blockIdx.x * 256 + threadIdx.x;
    int r = i >> 6, c = i & 63;
    d[i] = (_Float16)s[r * 96 + c];
}

// ---------------------------------------------------------------------------
// qkv f32 [b][l][3072] -> qh,kh f16 [b][h][l][hd], vth f16 [b][h][hd][l]
// ---------------------------------------------------------------------------
__global__ __launch_bounds__(256) void repack_attn(
    const float* __restrict__ qkv,
    _Float16* __restrict__ qh, _Float16* __restrict__ kh,
    _Float16* __restrict__ vth)
{
    const int lt = blockIdx.x & 15;
    const int h  = (blockIdx.x >> 4) & (NH_SZ - 1);
    const int b  = blockIdx.x >> 8;
    const int tid = threadIdx.x;
    const int r  = tid >> 2;
    const int c0 = (tid & 3) * 16;

    const size_t srcrow = (size_t)(b * L_SZ + lt * 64 + r) * 3072 + h * 64;
    _Float16* qdst = qh + ((size_t)(b * NH_SZ + h) * L_SZ + lt * 64 + r) * HD_SZ;
    _Float16* kdst = kh + ((size_t)(b * NH_SZ + h) * L_SZ + lt * 64 + r) * HD_SZ;

    __shared__ float Vf[64 * 65];
#pragma unroll
    for (int u = 0; u < 4; u++) {
        int c = c0 + u * 4;
        float4 vq = *(const float4*)&qkv[srcrow + c];
        float4 vk = *(const float4*)&qkv[srcrow + 1024 + c];
        float4 vv = *(const float4*)&qkv[srcrow + 2048 + c];
        half4v oq = {(_Float16)vq.x, (_Float16)vq.y, (_Float16)vq.z, (_Float16)vq.w};
        half4v ok = {(_Float16)vk.x, (_Float16)vk.y, (_Float16)vk.z, (_Float16)vk.w};
        *(half4v*)&qdst[c] = oq;
        *(half4v*)&kdst[c] = ok;
        Vf[r * 65 + c + 0] = vv.x;
        Vf[r * 65 + c + 1] = vv.y;
        Vf[r * 65 + c + 2] = vv.z;
        Vf[r * 65 + c + 3] = vv.w;
    }
    __syncthreads();
    const int hd = tid >> 2;
    const int l0 = (tid & 3) * 16;
    _Float16* dst = vth + ((size_t)(b * NH_SZ + h) * HD_SZ + hd) * L_SZ + lt * 64 + l0;
#pragma unroll
    for (int kk = 0; kk < 16; kk += 2) {
        half2v o = {(_Float16)Vf[(l0 + kk) * 65 + hd],
                    (_Float16)Vf[(l0 + kk + 1) * 65 + hd]};
        *(half2v*)&dst[kk] = o;
    }
}

// ---------------------------------------------------------------------------
// Barrier-free MFMA flash attention.
// Block = (b, h, 64-q-row tile); each of 4 waves independently owns 16 q rows
// and iterates all keys. K/V fragments load global->register (no staging).
// Only LDS use: per-wave P transform (C layout -> A layout), wave-internal.
// Softmax in exp2 domain.
// ---------------------------------------------------------------------------
__global__ __launch_bounds__(256) void attn_mfma(
    const _Float16* __restrict__ qh, const _Float16* __restrict__ kh,
    const _Float16* __restrict__ vth, const int* __restrict__ mask,
    _Float16* __restrict__ ctxh)
{
    const int qt = blockIdx.x & 15;
    const int h  = (blockIdx.x >> 4) & (NH_SZ - 1);
    const int b  = blockIdx.x >> 8;
    const int tid = threadIdx.x;
    const int wave = tid >> 6;
    const int lane = tid & 63;
    const int fr = lane & 15;
    const int g  = lane >> 4;
    const int fq = g * 8;
    const int g4 = g * 4;

    __shared__ __align__(16) _Float16 Ps[4][16 * 72];

    const int q0 = qt * 64 + wave * 16;
    const _Float16* qbase = qh + ((size_t)(b * NH_SZ + h) * L_SZ + q0) * HD_SZ;
    const _Float16* kbase = kh + (size_t)(b * NH_SZ + h) * L_SZ * HD_SZ;
    const _Float16* vbase = vth + (size_t)(b * NH_SZ + h) * HD_SZ * L_SZ;

    // Q A-fragments straight from global: A[m=fr][k=fq+j (+32)]
    half8v aQ0 = *(const half8v*)&qbase[fr * 64 + fq];
    half8v aQ1 = *(const half8v*)&qbase[fr * 64 + 32 + fq];

    const float SC2 = 0.125f * L2E;   // score scale folded with log2(e)

    float m_run[4] = {-1e30f, -1e30f, -1e30f, -1e30f};
    float l_run[4] = {0.f, 0.f, 0.f, 0.f};
    floatx4 zero = {0.f, 0.f, 0.f, 0.f};
    floatx4 accO[4];
#pragma unroll
    for (int jn = 0; jn < 4; jn++) accO[jn] = zero;

    for (int kb = 0; kb < L_SZ / 64; kb++) {
        const int k0 = kb * 64;

        // S = Q @ K^T  (16 q rows x 64 keys), K frags direct from global
        floatx4 sc[4];
#pragma unroll
        for (int jn = 0; jn < 4; jn++) {
            half8v bk0 = *(const half8v*)&kbase[(size_t)(k0 + jn * 16 + fr) * 64 + fq];
            half8v bk1 = *(const half8v*)&kbase[(size_t)(k0 + jn * 16 + fr) * 64 + 32 + fq];
            floatx4 t = __builtin_amdgcn_mfma_f32_16x16x32_f16(aQ0, bk0, zero, 0, 0, 0);
            sc[jn] = __builtin_amdgcn_mfma_f32_16x16x32_f16(aQ1, bk1, t, 0, 0, 0);
        }

        // scale + mask in exp2 domain
        float s[4][4], p[4][4];
#pragma unroll
        for (int jn = 0; jn < 4; jn++) {
            float ml = L2E * (float)mask[b * L_SZ + k0 + jn * 16 + fr];
#pragma unroll
            for (int r = 0; r < 4; r++) s[jn][r] = sc[jn][r] * SC2 + ml;
        }
        // online softmax; row g4+r lives across the 16 fr-lanes of group g
#pragma unroll
        for (int r = 0; r < 4; r++) {
            float tm = fmaxf(fmaxf(s[0][r], s[1][r]), fmaxf(s[2][r], s[3][r]));
#pragma unroll
            for (int off = 1; off < 16; off <<= 1) tm = fmaxf(tm, __shfl_xor(tm, off));
            float mn = fmaxf(m_run[r], tm);
            float alpha = __builtin_amdgcn_exp2f(m_run[r] - mn);
            float rs = 0.f;
#pragma unroll
            for (int jn = 0; jn < 4; jn++) {
                float pv = __builtin_amdgcn_exp2f(s[jn][r] - mn);
                p[jn][r] = pv;
                rs += pv;
            }
#pragma unroll
            for (int off = 1; off < 16; off <<= 1) rs += __shfl_xor(rs, off);
            l_run[r] = l_run[r] * alpha + rs;
            m_run[r] = mn;
#pragma unroll
            for (int jn = 0; jn < 4; jn++) accO[jn][r] *= alpha;
        }

        // P: C layout -> A layout via per-wave LDS (wave-internal ordering)
#pragma unroll
        for (int jn = 0; jn < 4; jn++)
#pragma unroll
            for (int r = 0; r < 4; r++)
                Ps[wave][(g4 + r) * 72 + jn * 16 + fr] = (_Float16)p[jn][r];
        asm volatile("s_waitcnt lgkmcnt(0)" ::: "memory");

        half8v aP0 = *(const half8v*)&Ps[wave][fr * 72 + fq];
        half8v aP1 = *(const half8v*)&Ps[wave][fr * 72 + 32 + fq];

        // O += P @ V, V^T frags direct from global
#pragma unroll
        for (int jn = 0; jn < 4; jn++) {
            half8v bv0 = *(const half8v*)&vbase[(size_t)(jn * 16 + fr) * L_SZ + k0 + fq];
            half8v bv1 = *(const half8v*)&vbase[(size_t)(jn * 16 + fr) * L_SZ + k0 + 32 + fq];
            accO[jn] = __builtin_amdgcn_mfma_f32_16x16x32_f16(aP0, bv0, accO[jn], 0, 0, 0);
            accO[jn] = __builtin_amdgcn_mfma_f32_16x16x32_f16(aP1, bv1, accO[jn], 0, 0, 0);
        }
    }

#pragma unroll
    for (int r = 0; r < 4; r++) {
        float inv = __builtin_amdgcn_rcpf(l_run[r]);
        int qrow = q0 + g4 + r;
#pragma unroll
        for (int jn = 0; jn < 4; jn++) {
            ctxh[((size_t)(b * L_SZ) + qrow) * H_SZ + h * 64 + jn * 16 + fr] =
                (_Float16)(accO[jn][r] * inv);
        }
    }
}

// ---------------------------------------------------------------------------
__device__ __forceinline__ float block_sum256(float v) {
    __shared__ float red[4];
#pragma unroll
    for (int off = 32; off; off >>= 1) v += __shfl_down(v, off);
    __syncthreads();
    if ((threadIdx.x & 63) == 0) red[threadIdx.x >> 6] = v;
    __syncthreads();
    return red[0] + red[1] + red[2] + red[3];
}

__global__ __launch_bounds__(256) void add_ln_kernel(
    const float* __restrict__ t_in, const float* __restrict__ x_in,
    const float* __restrict__ w, const float* __restrict__ bparm,
    float* __restrict__ out)
{
    const int row = blockIdx.x;
    const int c0 = threadIdx.x * 4;
    float4 tv = *(const float4*)(t_in + (size_t)row * H_SZ + c0);
    float4 xv = *(const float4*)(x_in + (size_t)row * H_SZ + c0);
    float vals[4] = {tv.x + xv.x, tv.y + xv.y, tv.z + xv.z, tv.w + xv.w};
    float xr[4] = {xv.x, xv.y, xv.z, xv.w};
    float s = vals[0] + vals[1] + vals[2] + vals[3];
    float mu = block_sum256(s) * (1.0f / H_SZ);
    float vs = 0.f;
#pragma unroll
    for (int i = 0; i < 4; i++) {
        float d = vals[i] - mu;
        vs += d * d;
    }
    float var = block_sum256(vs) * (1.0f / H_SZ);
    float inv = rsqrtf(var + 1e-12f);
#pragma unroll
    for (int i = 0; i < 4; i++) {
        int c = c0 + i;
        out[(size_t)row * H_SZ + c] =
            (vals[i] - mu) * inv * w[c] + bparm[c] + xr[i];
    }
}

__global__ __launch_bounds__(256) void rmsnorm_h_kernel(
    const float* __restrict__ x, const float* __restrict__ w,
    _Float16* __restrict__ out)
{
    const int row = blockIdx.x;
    const int c0 = threadIdx.x * 4;
    float4 xv = *(const float4*)(x + (size_t)row * H_SZ + c0);
    float vals[4] = {xv.x, xv.y, xv.z, xv.w};
    float s = vals[0]*vals[0] + vals[1]*vals[1] + vals[2]*vals[2] + vals[3]*vals[3];
    float ms = block_sum256(s) * (1.0f / H_SZ);
    float inv = rsqrtf(ms + 1e-6f);
    half4v o;
#pragma unroll
    for (int i = 0; i < 4; i++) o[i] = (_Float16)(vals[i] * inv * w[c0 + i]);
    *(half4v*)&out[(size_t)row * H_SZ + c0] = o;
}

__global__ __launch_bounds__(256) void rmsnorm_kernel(
    const float* __restrict__ x, const float* __restrict__ add,
    const float* __restrict__ w, float* __restrict__ out)
{
    const int row = blockIdx.x;
    const int c0 = threadIdx.x * 4;
    float4 xv = *(const float4*)(x + (size_t)row * H_SZ + c0);
    float vals[4] = {xv.x, xv.y, xv.z, xv.w};
    if (add) {
        float4 av = *(const float4*)(add + (size_t)row * H_SZ + c0);
        vals[0] += av.x; vals[1] += av.y; vals[2] += av.z; vals[3] += av.w;
    }
    float s = vals[0]*vals[0] + vals[1]*vals[1] + vals[2]*vals[2] + vals[3]*vals[3];
    float ms = block_sum256(s) * (1.0f / H_SZ);
    float inv = rsqrtf(ms + 1e-6f);
#pragma unroll
    for (int i = 0; i < 4; i++) {
        int c = c0 + i;
        out[(size_t)row * H_SZ + c] = vals[i] * inv * w[c];
    }
}

__global__ __launch_bounds__(256) void conv_silu_kernel(
    const float* __restrict__ proj, const int* __restrict__ mask,
    const float* __restrict__ conv_w, const float* __restrict__ conv_b,
    float* __restrict__ ssm_f, _Float16* __restrict__ ssm_h)
{
    const int idx = blockIdx.x * 256 + threadIdx.x;
    const int d = idx & (DIN - 1);
    const int l = (idx >> 11) & (L_SZ - 1);
    const int b = idx >> 21;
    float acc = conv_b[d];
#pragma unroll
    for (int j = 0; j < KCONV; j++) {
        int lp = l - (KCONV - 1) + j;
        if (lp >= 0) {
            float hv = proj[(size_t)(b * L_SZ + lp) * (2 * DIN) + d] *
                       (float)mask[b * L_SZ + lp];
            acc = fmaf(hv, conv_w[d * KCONV + j], acc);
        }
    }
    float r = acc * sigmoid_fast(acc) * (float)mask[b * L_SZ + l];
    ssm_f[idx] = r;
    ssm_h[idx] = (_Float16)r;
}

// ---------------------------------------------------------------------------
// Chunked selective scan (fast exp2 path)
// ---------------------------------------------------------------------------
__global__ __launch_bounds__(256) void scan_pass1(
    const float* __restrict__ dt_lin, const float* __restrict__ dt_b,
    const float* __restrict__ A_log, const float* __restrict__ dbc,
    const float* __restrict__ ssm_in,
    float* __restrict__ P, float* __restrict__ S)
{
    const int g = blockIdx.x & 7;
    const int c = (blockIdx.x >> 3) & (NC - 1);
    const int b = blockIdx.x >> 8;
    const int d = g * 256 + threadIdx.x;
    const int row0 = b * L_SZ + c * CL;

    __shared__ float BCs[CL][32];
#pragma unroll
    for (int it = 0; it < (CL * 32) / 256; it++) {
        int i = threadIdx.x + it * 256;
        int l = i >> 5, j = i & 31;
        BCs[l][j] = dbc[(size_t)(row0 + l) * 96 + DTR + j];
    }
    __syncthreads();

    float Aa2[NST];   // -exp(A_log) * log2(e)
#pragma unroll
    for (int n = 0; n < NST; n++) Aa2[n] = -exp_fast(A_log[d * NST + n]) * L2E;
    const float dtb = dt_b[d];

    float st[NST] = {};
    float sdt = 0.f;

    for (int l = 0; l < CL; l++) {
        const size_t row = (size_t)(row0 + l);
        float dtv = softplus_f(dt_lin[row * DIN + d] + dtb);
        float u = ssm_in[row * DIN + d];
        float du = dtv * u;
        sdt += dtv;
#pragma unroll
        for (int n = 0; n < NST; n++) {
            float dA = __builtin_amdgcn_exp2f(dtv * Aa2[n]);
            st[n] = fmaf(dA, st[n], du * BCs[l][n]);
        }
    }
    const size_t base = ((size_t)(b * NC + c) * NST) * DIN + d;
#pragma unroll
    for (int n = 0; n < NST; n++) {
        P[base + (size_t)n * DIN] = __builtin_amdgcn_exp2f(sdt * Aa2[n]);
        S[base + (size_t)n * DIN] = st[n];
    }
}

// parallel over (b, n, d)
__global__ __launch_bounds__(256) void scan_combine(
    const float* __restrict__ P, const float* __restrict__ S,
    float* __restrict__ I)
{
    const int idx = blockIdx.x * 256 + threadIdx.x;
    const int d = idx & (DIN - 1);
    const int n = (idx >> 11) & (NST - 1);
    const int b = idx >> 15;
    float st = 0.f;
#pragma unroll 4
    for (int c = 0; c < NC; c++) {
        const size_t o = ((size_t)((b * NC + c) * NST) + n) * DIN + d;
        float pv = P[o], sv = S[o];
        I[o] = st;
        st = fmaf(pv, st, sv);
    }
}

__global__ __launch_bounds__(256) void scan_pass2(
    const float* __restrict__ dt_lin, const float* __restrict__ dt_b,
    const float* __restrict__ A_log, const float* __restrict__ dbc,
    const float* __restrict__ ssm_in, const float* __restrict__ I,
    const float* __restrict__ D_skip, const float* __restrict__ proj,
    _Float16* __restrict__ scan_out)
{
    const int g = blockIdx.x & 7;
    const int c = (blockIdx.x >> 3) & (NC - 1);
    const int b = blockIdx.x >> 8;
    const int d = g * 256 + threadIdx.x;
    const int row0 = b * L_SZ + c * CL;

    __shared__ float BCs[CL][32];
#pragma unroll
    for (int it = 0; it < (CL * 32) / 256; it++) {
        int i = threadIdx.x + it * 256;
        int l = i >> 5, j = i & 31;
        BCs[l][j] = dbc[(size_t)(row0 + l) * 96 + DTR + j];
    }
    __syncthreads();

    float Aa2[NST];
#pragma unroll
    for (int n = 0; n < NST; n++) Aa2[n] = -exp_fast(A_log[d * NST + n]) * L2E;
    const float dtb = dt_b[d];
    const float dsk = D_skip[d];

    float st[NST];
    const size_t ibase = ((size_t)(b * NC + c) * NST) * DIN + d;
#pragma unroll
    for (int n = 0; n < NST; n++) st[n] = I[ibase + (size_t)n * DIN];

    for (int l = 0; l < CL; l++) {
        const size_t row = (size_t)(row0 + l);
        float dtv = softplus_f(dt_lin[row * DIN + d] + dtb);
        float u = ssm_in[row * DIN + d];
        float du = dtv * u;
        float y = 0.f;
#pragma unroll
        for (int n = 0; n < NST; n++) {
            float dA = __builtin_amdgcn_exp2f(dtv * Aa2[n]);
            st[n] = fmaf(dA, st[n], du * BCs[l][n]);
            y = fmaf(st[n], BCs[l][NST + n], y);
        }
        float gv = proj[row * (2 * DIN) + DIN + d];
        float sg = gv * sigmoid_fast(gv);
        scan_out[row * DIN + d] = (_Float16)((y + u * dsk) * sg);
    }
}

// ---------------------------------------------------------------------------
extern "C" void kernel_launch(void* const* d_in, const int* in_sizes, int n_in,
                              void* d_out, int out_size, void* d_ws, size_t ws_size,
                              hipStream_t stream) {
    const float* x      = (const float*)d_in[0];
    const int*   mask   = (const int*)d_in[1];
    const float* Wq     = (const float*)d_in[2];
    const float* bq     = (const float*)d_in[3];
    const float* Wk     = (const float*)d_in[4];
    const float* bk     = (const float*)d_in[5];
    const float* Wv     = (const float*)d_in[6];
    const float* bv     = (const float*)d_in[7];
    const float* Wo     = (const float*)d_in[8];
    const float* bo     = (const float*)d_in[9];
    const float* ln_w   = (const float*)d_in[10];
    const float* ln_b   = (const float*)d_in[11];
    const float* mnw    = (const float*)d_in[12];
    const float* in_proj_w = (const float*)d_in[13];
    const float* conv_w = (const float*)d_in[14];
    const float* conv_b = (const float*)d_in[15];
    const float* x_proj_w = (const float*)d_in[16];
    const float* dt_proj_w = (const float*)d_in[17];
    const float* dt_proj_b = (const float*)d_in[18];
    const float* A_log  = (const float*)d_in[19];
    const float* D_skip = (const float*)d_in[20];
    const float* out_proj_w = (const float*)d_in[21];
    const float* fnw    = (const float*)d_in[22];
    float* out = (float*)d_out;
    (void)ws_size; (void)n_in; (void)in_sizes; (void)out_size;

    float* ws = (float*)d_ws;
    const size_t F1 = 1u << 20;
    _Float16* Wqkvh = (_Float16*)(ws + 0);
    _Float16* Woh  = (_Float16*)(ws + 3 * F1 / 2);
    _Float16* inph = (_Float16*)(ws + 2 * F1);
    _Float16* outph= (_Float16*)(ws + 4 * F1);
    _Float16* xprh = (_Float16*)(ws + 5 * F1);
    _Float16* dtph = (_Float16*)(ws + 5 * F1 + F1 / 8);
    float* bqkv    = ws + 5 * F1 + 3 * F1 / 16;
    _Float16* xh   = (_Float16*)(ws + 5 * F1 + F1 / 4);
    float* x2      = ws + 6 * F1 + F1 / 4;
    float* proj    = ws + 8 * F1 + F1 / 2;
    float* qkv     = proj;
    float* x3      = proj;
    _Float16* ctxh = (_Float16*)(ws + 16 * F1 + F1 / 2);
    _Float16* dbch = (_Float16*)(ws + 16 * F1 + F1 / 2);
    float* dbc     = ws + 16 * F1 + 3 * F1 / 4;
    float* attn_tmp= ws + 17 * F1 + F1 / 2;
    _Float16* ssmh = (_Float16*)attn_tmp;
    float* Pbuf    = attn_tmp;
    float* Ibuf    = Pbuf;
    _Float16* hh   = (_Float16*)(ws + 19 * F1 + F1 / 2);
    float* ssm     = ws + 20 * F1 + F1 / 2;
    float* dtl     = ws + 24 * F1 + F1 / 2;
    _Float16* qh16 = (_Float16*)(ws + 24 * F1 + F1 / 2);
    _Float16* kh16 = (_Float16*)(ws + 25 * F1 + F1 / 2);
    _Float16* vth16= (_Float16*)(ws + 26 * F1 + F1 / 2);
    float* Sbuf    = ws + 28 * F1 + F1 / 2;
    _Float16* sob  = (_Float16*)Sbuf;

    const int M = B_SZ * L_SZ;
    dim3 blk(256);

    cast_all<<<dim3(CAST_TOTAL / 256), blk, 0, stream>>>(
        Wq, Wk, Wv, Wo, in_proj_w, out_proj_w, dt_proj_w, x, x_proj_w,
        bq, bk, bv, Wqkvh, Woh, inph, outph, dtph, xh, xprh, bqkv);

    hgemm<<<dim3(24, 16), blk, 0, stream>>>(xh, H_SZ, Wqkvh, H_SZ, bqkv, qkv, 3 * H_SZ, 3 * H_SZ, H_SZ);

    repack_attn<<<512, blk, 0, stream>>>(qkv, qh16, kh16, vth16);
    attn_mfma<<<512, blk, 0, stream>>>(qh16, kh16, vth16, mask, ctxh);

    hgemm<<<dim3(8, 16), blk, 0, stream>>>(ctxh, H_SZ, Woh, H_SZ, bo, attn_tmp, H_SZ, H_SZ, H_SZ);
    add_ln_kernel<<<dim3(M), blk, 0, stream>>>(attn_tmp, x, ln_w, ln_b, x2);

    rmsnorm_h_kernel<<<dim3(M), blk, 0, stream>>>(x2, mnw, hh);
    hgemm<<<dim3(32, 16), blk, 0, stream>>>(hh, H_SZ, inph, H_SZ, nullptr, proj, 2 * DIN, 2 * DIN, H_SZ);

    conv_silu_kernel<<<dim3(B_SZ * L_SZ * DIN / 256), blk, 0, stream>>>(proj, mask, conv_w, conv_b, ssm, ssmh);

    hgemm<<<dim3(1, 16), blk, 0, stream>>>(ssmh, DIN, xprh, DIN, nullptr, dbc, 96, 96, DIN);
    pack_dbc_kernel<<<512, blk, 0, stream>>>(dbc, dbch);
    hgemm<<<dim3(16, 16), blk, 0, stream>>>(dbch, DTR, dtph, DTR, nullptr, dtl, DIN, DIN, DTR);

    scan_pass1<<<dim3(B_SZ * NC * (DIN / 256)), blk, 0, stream>>>(dtl, dt_proj_b, A_log, dbc, ssm, Pbuf, Sbuf);
    scan_combine<<<dim3(B_SZ * NST * DIN / 256), blk, 0, stream>>>(Pbuf, Sbuf, Ibuf);
    scan_pass2<<<dim3(B_SZ * NC * (DIN / 256)), blk, 0, stream>>>(dtl, dt_proj_b, A_log, dbc, ssm, Ibuf, D_skip, proj, sob);

    hgemm<<<dim3(8, 16), blk, 0, stream>>>(sob, DIN, outph, DIN, nullptr, x3, H_SZ, H_SZ, DIN);
    rmsnorm_kernel<<<dim3(M), blk, 0, stream>>>(x2, x3, fnw, out);
}

// Round 7
// 477.827 us; speedup vs baseline: 8.7189x; 1.0168x over previous
//
#include <hip/hip_runtime.h>
#include <math.h>

#define B_SZ 2
#define L_SZ 1024
#define H_SZ 1024
#define NH_SZ 16
#define HD_SZ 64
#define DIN 2048
#define NST 16
#define KCONV 4
#define DTR 64

#define NC 32   // scan chunks
#define CL 32   // chunk length

#define L2E 1.4426950408889634f
#define LN2 0.6931471805599453f

typedef _Float16 half8v __attribute__((ext_vector_type(8)));
typedef _Float16 half4v __attribute__((ext_vector_type(4)));
typedef _Float16 half2v __attribute__((ext_vector_type(2)));
typedef float floatx4 __attribute__((ext_vector_type(4)));

__device__ __forceinline__ float exp_fast(float x) {
    return __builtin_amdgcn_exp2f(x * L2E);
}
__device__ __forceinline__ float softplus_f(float x) {
    if (x > 20.f) return x;
    float e = __builtin_amdgcn_exp2f(x * L2E);
    return LN2 * __builtin_amdgcn_logf(1.0f + e);
}
__device__ __forceinline__ float sigmoid_fast(float x) {
    return __builtin_amdgcn_rcpf(1.0f + __builtin_amdgcn_exp2f(-x * L2E));
}

// ---------------------------------------------------------------------------
// MFMA f16 GEMM: C[M,N] = A[M,K] @ W[N,K]^T + bias.  M mult of 128, K mult 32.
// ---------------------------------------------------------------------------
__global__ __launch_bounds__(256) void hgemm(
    const _Float16* __restrict__ A, int lda,
    const _Float16* __restrict__ W, int ldw,
    const float* __restrict__ bias,
    float* __restrict__ C, int ldc,
    int N, int K)
{
    __shared__ __align__(16) _Float16 As[128 * 32];
    __shared__ __align__(16) _Float16 Bs[128 * 32];
    const int tid = threadIdx.x;
    const int m0 = blockIdx.y * 128;
    const int n0 = blockIdx.x * 128;
    const int wave = tid >> 6;
    const int lane = tid & 63;
    const int wm = (wave >> 1) * 64;
    const int wn = (wave & 1) * 64;
    const int row_l = tid >> 2;
    const int col_l = (tid & 3) * 8;

    floatx4 zero = {0.f, 0.f, 0.f, 0.f};
    floatx4 acc[4][4];
#pragma unroll
    for (int i = 0; i < 4; i++)
#pragma unroll
        for (int j = 0; j < 4; j++) acc[i][j] = zero;

    const int fr = lane & 15;
    const int fq = (lane >> 4) * 8;

    for (int k0 = 0; k0 < K; k0 += 32) {
        *(half8v*)&As[row_l * 32 + col_l] =
            *(const half8v*)&A[(size_t)(m0 + row_l) * lda + k0 + col_l];
        *(half8v*)&As[(row_l + 64) * 32 + col_l] =
            *(const half8v*)&A[(size_t)(m0 + row_l + 64) * lda + k0 + col_l];
        *(half8v*)&Bs[row_l * 32 + col_l] =
            *(const half8v*)&W[(size_t)(n0 + row_l) * ldw + k0 + col_l];
        *(half8v*)&Bs[(row_l + 64) * 32 + col_l] =
            *(const half8v*)&W[(size_t)(n0 + row_l + 64) * ldw + k0 + col_l];
        __syncthreads();

        half8v af[4], bf[4];
#pragma unroll
        for (int i = 0; i < 4; i++)
            af[i] = *(const half8v*)&As[(wm + i * 16 + fr) * 32 + fq];
#pragma unroll
        for (int j = 0; j < 4; j++)
            bf[j] = *(const half8v*)&Bs[(wn + j * 16 + fr) * 32 + fq];
#pragma unroll
        for (int i = 0; i < 4; i++)
#pragma unroll
            for (int j = 0; j < 4; j++)
                acc[i][j] = __builtin_amdgcn_mfma_f32_16x16x32_f16(
                    af[i], bf[j], acc[i][j], 0, 0, 0);
        __syncthreads();
    }

    const int er = (lane >> 4) * 4;
    const int ec = lane & 15;
#pragma unroll
    for (int j = 0; j < 4; j++) {
        int n = n0 + wn + j * 16 + ec;
        if (n < N) {
            float bv = bias ? bias[n] : 0.f;
#pragma unroll
            for (int i = 0; i < 4; i++) {
#pragma unroll
                for (int r = 0; r < 4; r++) {
                    int m = m0 + wm + i * 16 + er + r;
                    C[(size_t)m * ldc + n] = acc[i][j][r] + bv;
                }
            }
        }
    }
}

// ---------------------------------------------------------------------------
// One combined cast kernel (vec4 items per segment)
// ---------------------------------------------------------------------------
#define SEG_QKVW 262144
#define SEG_WO   262144
#define SEG_INP  1048576
#define SEG_OUTP 524288
#define SEG_DTP  32768
#define SEG_X    524288
#define SEG_XPR  65536
#define SEG_BQKV 768
#define CAST_TOTAL (SEG_QKVW*3 + SEG_WO + SEG_INP + SEG_OUTP + SEG_DTP + SEG_X + SEG_XPR + SEG_BQKV)

__device__ __forceinline__ void cast4(const float* __restrict__ s,
                                      _Float16* __restrict__ d, int i) {
    float4 v = *(const float4*)&s[i * 4];
    half4v o = {(_Float16)v.x, (_Float16)v.y, (_Float16)v.z, (_Float16)v.w};
    *(half4v*)&d[i * 4] = o;
}

__global__ __launch_bounds__(256) void cast_all(
    const float* __restrict__ Wq, const float* __restrict__ Wk,
    const float* __restrict__ Wv, const float* __restrict__ Wo,
    const float* __restrict__ inp, const float* __restrict__ outp,
    const float* __restrict__ dtp, const float* __restrict__ x,
    const float* __restrict__ xpr,
    const float* __restrict__ bq, const float* __restrict__ bk,
    const float* __restrict__ bv,
    _Float16* __restrict__ Wqkvh, _Float16* __restrict__ Woh,
    _Float16* __restrict__ inph, _Float16* __restrict__ outph,
    _Float16* __restrict__ dtph, _Float16* __restrict__ xh,
    _Float16* __restrict__ xprh, float* __restrict__ bqkv)
{
    int i = blockIdx.x * 256 + threadIdx.x;
    if (i < SEG_QKVW) { cast4(Wq, Wqkvh, i); return; }
    i -= SEG_QKVW;
    if (i < SEG_QKVW) { cast4(Wk, Wqkvh + H_SZ * H_SZ, i); return; }
    i -= SEG_QKVW;
    if (i < SEG_QKVW) { cast4(Wv, Wqkvh + 2 * H_SZ * H_SZ, i); return; }
    i -= SEG_QKVW;
    if (i < SEG_WO)   { cast4(Wo, Woh, i); return; }
    i -= SEG_WO;
    if (i < SEG_INP)  { cast4(inp, inph, i); return; }
    i -= SEG_INP;
    if (i < SEG_OUTP) { cast4(outp, outph, i); return; }
    i -= SEG_OUTP;
    if (i < SEG_DTP)  { cast4(dtp, dtph, i); return; }
    i -= SEG_DTP;
    if (i < SEG_X)    { cast4(x, xh, i); return; }
    i -= SEG_X;
    if (i < SEG_XPR) {
        int e = i * 4;
        int r = e >> 11;
        if (r < 96) {
            cast4(xpr, xprh, i);
        } else {
            half4v z = {(_Float16)0.f, (_Float16)0.f, (_Float16)0.f, (_Float16)0.f};
            *(half4v*)&xprh[e] = z;
        }
        return;
    }
    i -= SEG_XPR;
    if (i < SEG_BQKV) {
        int e = i * 4;
        const float* src = (e < 1024) ? (bq + e) : (e < 2048) ? (bk + e - 1024) : (bv + e - 2048);
        *(float4*)&bqkv[e] = *(const float4*)src;
    }
}

// pack dbc[:, :64] (stride 96) -> [2048,64] f16
__global__ __launch_bounds__(256) void pack_dbc_kernel(
    const float* __restrict__ s, _Float16* __restrict__ d)
{
    int i = blockIdx.x * 256 + threadIdx.x;
    int r = i >> 6, c = i & 63;
    d[i] = (_Float16)s[r * 96 + c];
}

// ---------------------------------------------------------------------------
// qkv f32 [b][l][3072] -> qh,kh f16 [b][h][l][hd], vth f16 [b][h][hd][l]
// ---------------------------------------------------------------------------
__global__ __launch_bounds__(256) void repack_attn(
    const float* __restrict__ qkv,
    _Float16* __restrict__ qh, _Float16* __restrict__ kh,
    _Float16* __restrict__ vth)
{
    const int lt = blockIdx.x & 15;
    const int h  = (blockIdx.x >> 4) & (NH_SZ - 1);
    const int b  = blockIdx.x >> 8;
    const int tid = threadIdx.x;
    const int r  = tid >> 2;
    const int c0 = (tid & 3) * 16;

    const size_t srcrow = (size_t)(b * L_SZ + lt * 64 + r) * 3072 + h * 64;
    _Float16* qdst = qh + ((size_t)(b * NH_SZ + h) * L_SZ + lt * 64 + r) * HD_SZ;
    _Float16* kdst = kh + ((size_t)(b * NH_SZ + h) * L_SZ + lt * 64 + r) * HD_SZ;

    __shared__ float Vf[64 * 65];
#pragma unroll
    for (int u = 0; u < 4; u++) {
        int c = c0 + u * 4;
        float4 vq = *(const float4*)&qkv[srcrow + c];
        float4 vk = *(const float4*)&qkv[srcrow + 1024 + c];
        float4 vv = *(const float4*)&qkv[srcrow + 2048 + c];
        half4v oq = {(_Float16)vq.x, (_Float16)vq.y, (_Float16)vq.z, (_Float16)vq.w};
        half4v ok = {(_Float16)vk.x, (_Float16)vk.y, (_Float16)vk.z, (_Float16)vk.w};
        *(half4v*)&qdst[c] = oq;
        *(half4v*)&kdst[c] = ok;
        Vf[r * 65 + c + 0] = vv.x;
        Vf[r * 65 + c + 1] = vv.y;
        Vf[r * 65 + c + 2] = vv.z;
        Vf[r * 65 + c + 3] = vv.w;
    }
    __syncthreads();
    const int hd = tid >> 2;
    const int l0 = (tid & 3) * 16;
    _Float16* dst = vth + ((size_t)(b * NH_SZ + h) * HD_SZ + hd) * L_SZ + lt * 64 + l0;
#pragma unroll
    for (int kk = 0; kk < 16; kk += 2) {
        half2v o = {(_Float16)Vf[(l0 + kk) * 65 + hd],
                    (_Float16)Vf[(l0 + kk + 1) * 65 + hd]};
        *(half2v*)&dst[kk] = o;
    }
}

// ---------------------------------------------------------------------------
// Split-K MFMA flash attention.
// Block = (b, h, 16 q-rows): grid 2048.  Each of 4 waves scans a disjoint
// 256-key quarter with its own online softmax; LDS epilogue merges partials.
// K/V fragments load global->register (no staging, no in-loop barriers).
// ---------------------------------------------------------------------------
__global__ __launch_bounds__(256) void attn_mfma(
    const _Float16* __restrict__ qh, const _Float16* __restrict__ kh,
    const _Float16* __restrict__ vth, const int* __restrict__ mask,
    _Float16* __restrict__ ctxh)
{
    const int qt = blockIdx.x & 63;
    const int h  = (blockIdx.x >> 6) & (NH_SZ - 1);
    const int b  = blockIdx.x >> 10;
    const int tid = threadIdx.x;
    const int wave = tid >> 6;
    const int lane = tid & 63;
    const int fr = lane & 15;
    const int g  = lane >> 4;
    const int fq = g * 8;
    const int g4 = g * 4;
    const int q0 = qt * 16;

    // union: Ps (P C->A transform, in-loop) / OS (O merge, epilogue)
    __shared__ __align__(16) unsigned char smem[4 * 16 * 68 * 4];  // 17408 B
    _Float16 (*Ps)[16 * 72] = (_Float16(*)[16 * 72])smem;          // 9216 B
    float (*OS)[16 * 68] = (float(*)[16 * 68])smem;
    __shared__ float mS[4][16];
    __shared__ float lS[4][16];

    const _Float16* qbase = qh + ((size_t)(b * NH_SZ + h) * L_SZ + q0) * HD_SZ;
    const _Float16* kbase = kh + (size_t)(b * NH_SZ + h) * L_SZ * HD_SZ;
    const _Float16* vbase = vth + (size_t)(b * NH_SZ + h) * HD_SZ * L_SZ;
    const int wk0 = wave * 256;   // this wave's key range start

    half8v aQ0 = *(const half8v*)&qbase[fr * 64 + fq];
    half8v aQ1 = *(const half8v*)&qbase[fr * 64 + 32 + fq];

    const float SC2 = 0.125f * L2E;

    float m_run[4] = {-1e30f, -1e30f, -1e30f, -1e30f};
    float l_run[4] = {0.f, 0.f, 0.f, 0.f};
    floatx4 zero = {0.f, 0.f, 0.f, 0.f};
    floatx4 accO[4];
#pragma unroll
    for (int jn = 0; jn < 4; jn++) accO[jn] = zero;

#pragma unroll
    for (int kb = 0; kb < 4; kb++) {
        const int k0 = wk0 + kb * 64;

        floatx4 sc[4];
#pragma unroll
        for (int jn = 0; jn < 4; jn++) {
            half8v bk0 = *(const half8v*)&kbase[(size_t)(k0 + jn * 16 + fr) * 64 + fq];
            half8v bk1 = *(const half8v*)&kbase[(size_t)(k0 + jn * 16 + fr) * 64 + 32 + fq];
            floatx4 t = __builtin_amdgcn_mfma_f32_16x16x32_f16(aQ0, bk0, zero, 0, 0, 0);
            sc[jn] = __builtin_amdgcn_mfma_f32_16x16x32_f16(aQ1, bk1, t, 0, 0, 0);
        }

        float s[4][4], p[4][4];
#pragma unroll
        for (int jn = 0; jn < 4; jn++) {
            float ml = L2E * (float)mask[b * L_SZ + k0 + jn * 16 + fr];
#pragma unroll
            for (int r = 0; r < 4; r++) s[jn][r] = sc[jn][r] * SC2 + ml;
        }
#pragma unroll
        for (int r = 0; r < 4; r++) {
            float tm = fmaxf(fmaxf(s[0][r], s[1][r]), fmaxf(s[2][r], s[3][r]));
#pragma unroll
            for (int off = 1; off < 16; off <<= 1) tm = fmaxf(tm, __shfl_xor(tm, off));
            float mn = fmaxf(m_run[r], tm);
            float alpha = __builtin_amdgcn_exp2f(m_run[r] - mn);
            float rs = 0.f;
#pragma unroll
            for (int jn = 0; jn < 4; jn++) {
                float pv = __builtin_amdgcn_exp2f(s[jn][r] - mn);
                p[jn][r] = pv;
                rs += pv;
            }
#pragma unroll
            for (int off = 1; off < 16; off <<= 1) rs += __shfl_xor(rs, off);
            l_run[r] = l_run[r] * alpha + rs;
            m_run[r] = mn;
#pragma unroll
            for (int jn = 0; jn < 4; jn++) accO[jn][r] *= alpha;
        }

        // P: C layout -> A layout via per-wave LDS (wave-internal ordering)
#pragma unroll
        for (int jn = 0; jn < 4; jn++)
#pragma unroll
            for (int r = 0; r < 4; r++)
                Ps[wave][(g4 + r) * 72 + jn * 16 + fr] = (_Float16)p[jn][r];
        asm volatile("s_waitcnt lgkmcnt(0)" ::: "memory");

        half8v aP0 = *(const half8v*)&Ps[wave][fr * 72 + fq];
        half8v aP1 = *(const half8v*)&Ps[wave][fr * 72 + 32 + fq];

#pragma unroll
        for (int jn = 0; jn < 4; jn++) {
            half8v bv0 = *(const half8v*)&vbase[(size_t)(jn * 16 + fr) * L_SZ + k0 + fq];
            half8v bv1 = *(const half8v*)&vbase[(size_t)(jn * 16 + fr) * L_SZ + k0 + 32 + fq];
            accO[jn] = __builtin_amdgcn_mfma_f32_16x16x32_f16(aP0, bv0, accO[jn], 0, 0, 0);
            accO[jn] = __builtin_amdgcn_mfma_f32_16x16x32_f16(aP1, bv1, accO[jn], 0, 0, 0);
        }
    }

    // ---- merge the 4 waves' partials ----
    if (fr == 0) {
#pragma unroll
        for (int r = 0; r < 4; r++) {
            mS[wave][g4 + r] = m_run[r];
            lS[wave][g4 + r] = l_run[r];
        }
    }
    __syncthreads();   // also guarantees all waves are done with Ps (union!)

#pragma unroll
    for (int r = 0; r < 4; r++) {
        int row = g4 + r;
        float M = fmaxf(fmaxf(mS[0][row], mS[1][row]), fmaxf(mS[2][row], mS[3][row]));
        float f = __builtin_amdgcn_exp2f(m_run[r] - M);
#pragma unroll
        for (int jn = 0; jn < 4; jn++) accO[jn][r] *= f;
    }
#pragma unroll
    for (int jn = 0; jn < 4; jn++)
#pragma unroll
        for (int r = 0; r < 4; r++)
            OS[wave][(g4 + r) * 68 + jn * 16 + fr] = accO[jn][r];
    __syncthreads();

    {
        int row = tid >> 4;
        int col0 = (tid & 15) * 4;
        float M = fmaxf(fmaxf(mS[0][row], mS[1][row]), fmaxf(mS[2][row], mS[3][row]));
        float Lt = lS[0][row] * __builtin_amdgcn_exp2f(mS[0][row] - M)
                 + lS[1][row] * __builtin_amdgcn_exp2f(mS[1][row] - M)
                 + lS[2][row] * __builtin_amdgcn_exp2f(mS[2][row] - M)
                 + lS[3][row] * __builtin_amdgcn_exp2f(mS[3][row] - M);
        float inv = __builtin_amdgcn_rcpf(Lt);
        floatx4 s0 = *(floatx4*)&OS[0][row * 68 + col0];
        floatx4 s1 = *(floatx4*)&OS[1][row * 68 + col0];
        floatx4 s2 = *(floatx4*)&OS[2][row * 68 + col0];
        floatx4 s3 = *(floatx4*)&OS[3][row * 68 + col0];
        floatx4 sum = s0 + s1 + s2 + s3;
        half4v o;
#pragma unroll
        for (int u = 0; u < 4; u++) o[u] = (_Float16)(sum[u] * inv);
        *(half4v*)&ctxh[((size_t)(b * L_SZ) + q0 + row) * H_SZ + h * 64 + col0] = o;
    }
}

// ---------------------------------------------------------------------------
__device__ __forceinline__ float block_sum256(float v) {
    __shared__ float red[4];
#pragma unroll
    for (int off = 32; off; off >>= 1) v += __shfl_down(v, off);
    __syncthreads();
    if ((threadIdx.x & 63) == 0) red[threadIdx.x >> 6] = v;
    __syncthreads();
    return red[0] + red[1] + red[2] + red[3];
}

__global__ __launch_bounds__(256) void add_ln_kernel(
    const float* __restrict__ t_in, const float* __restrict__ x_in,
    const float* __restrict__ w, const float* __restrict__ bparm,
    float* __restrict__ out)
{
    const int row = blockIdx.x;
    const int c0 = threadIdx.x * 4;
    float4 tv = *(const float4*)(t_in + (size_t)row * H_SZ + c0);
    float4 xv = *(const float4*)(x_in + (size_t)row * H_SZ + c0);
    float vals[4] = {tv.x + xv.x, tv.y + xv.y, tv.z + xv.z, tv.w + xv.w};
    float xr[4] = {xv.x, xv.y, xv.z, xv.w};
    float s = vals[0] + vals[1] + vals[2] + vals[3];
    float mu = block_sum256(s) * (1.0f / H_SZ);
    float vs = 0.f;
#pragma unroll
    for (int i = 0; i < 4; i++) {
        float d = vals[i] - mu;
        vs += d * d;
    }
    float var = block_sum256(vs) * (1.0f / H_SZ);
    float inv = rsqrtf(var + 1e-12f);
#pragma unroll
    for (int i = 0; i < 4; i++) {
        int c = c0 + i;
        out[(size_t)row * H_SZ + c] =
            (vals[i] - mu) * inv * w[c] + bparm[c] + xr[i];
    }
}

__global__ __launch_bounds__(256) void rmsnorm_h_kernel(
    const float* __restrict__ x, const float* __restrict__ w,
    _Float16* __restrict__ out)
{
    const int row = blockIdx.x;
    const int c0 = threadIdx.x * 4;
    float4 xv = *(const float4*)(x + (size_t)row * H_SZ + c0);
    float vals[4] = {xv.x, xv.y, xv.z, xv.w};
    float s = vals[0]*vals[0] + vals[1]*vals[1] + vals[2]*vals[2] + vals[3]*vals[3];
    float ms = block_sum256(s) * (1.0f / H_SZ);
    float inv = rsqrtf(ms + 1e-6f);
    half4v o;
#pragma unroll
    for (int i = 0; i < 4; i++) o[i] = (_Float16)(vals[i] * inv * w[c0 + i]);
    *(half4v*)&out[(size_t)row * H_SZ + c0] = o;
}

__global__ __launch_bounds__(256) void rmsnorm_kernel(
    const float* __restrict__ x, const float* __restrict__ add,
    const float* __restrict__ w, float* __restrict__ out)
{
    const int row = blockIdx.x;
    const int c0 = threadIdx.x * 4;
    float4 xv = *(const float4*)(x + (size_t)row * H_SZ + c0);
    float vals[4] = {xv.x, xv.y, xv.z, xv.w};
    if (add) {
        float4 av = *(const float4*)(add + (size_t)row * H_SZ + c0);
        vals[0] += av.x; vals[1] += av.y; vals[2] += av.z; vals[3] += av.w;
    }
    float s = vals[0]*vals[0] + vals[1]*vals[1] + vals[2]*vals[2] + vals[3]*vals[3];
    float ms = block_sum256(s) * (1.0f / H_SZ);
    float inv = rsqrtf(ms + 1e-6f);
#pragma unroll
    for (int i = 0; i < 4; i++) {
        int c = c0 + i;
        out[(size_t)row * H_SZ + c] = vals[i] * inv * w[c];
    }
}

__global__ __launch_bounds__(256) void conv_silu_kernel(
    const float* __restrict__ proj, const int* __restrict__ mask,
    const float* __restrict__ conv_w, const float* __restrict__ conv_b,
    float* __restrict__ ssm_f, _Float16* __restrict__ ssm_h)
{
    const int idx = blockIdx.x * 256 + threadIdx.x;
    const int d = idx & (DIN - 1);
    const int l = (idx >> 11) & (L_SZ - 1);
    const int b = idx >> 21;
    float acc = conv_b[d];
#pragma unroll
    for (int j = 0; j < KCONV; j++) {
        int lp = l - (KCONV - 1) + j;
        if (lp >= 0) {
            float hv = proj[(size_t)(b * L_SZ + lp) * (2 * DIN) + d] *
                       (float)mask[b * L_SZ + lp];
            acc = fmaf(hv, conv_w[d * KCONV + j], acc);
        }
    }
    float r = acc * sigmoid_fast(acc) * (float)mask[b * L_SZ + l];
    ssm_f[idx] = r;
    ssm_h[idx] = (_Float16)r;
}

// ---------------------------------------------------------------------------
// Chunked selective scan (fast exp2 path)
// ---------------------------------------------------------------------------
__global__ __launch_bounds__(256) void scan_pass1(
    const float* __restrict__ dt_lin, const float* __restrict__ dt_b,
    const float* __restrict__ A_log, const float* __restrict__ dbc,
    const float* __restrict__ ssm_in,
    float* __restrict__ P, float* __restrict__ S)
{
    const int g = blockIdx.x & 7;
    const int c = (blockIdx.x >> 3) & (NC - 1);
    const int b = blockIdx.x >> 8;
    const int d = g * 256 + threadIdx.x;
    const int row0 = b * L_SZ + c * CL;

    __shared__ float BCs[CL][32];
#pragma unroll
    for (int it = 0; it < (CL * 32) / 256; it++) {
        int i = threadIdx.x + it * 256;
        int l = i >> 5, j = i & 31;
        BCs[l][j] = dbc[(size_t)(row0 + l) * 96 + DTR + j];
    }
    __syncthreads();

    float Aa2[NST];
#pragma unroll
    for (int n = 0; n < NST; n++) Aa2[n] = -exp_fast(A_log[d * NST + n]) * L2E;
    const float dtb = dt_b[d];

    float st[NST] = {};
    float sdt = 0.f;

    for (int l = 0; l < CL; l++) {
        const size_t row = (size_t)(row0 + l);
        float dtv = softplus_f(dt_lin[row * DIN + d] + dtb);
        float u = ssm_in[row * DIN + d];
        float du = dtv * u;
        sdt += dtv;
#pragma unroll
        for (int n = 0; n < NST; n++) {
            float dA = __builtin_amdgcn_exp2f(dtv * Aa2[n]);
            st[n] = fmaf(dA, st[n], du * BCs[l][n]);
        }
    }
    const size_t base = ((size_t)(b * NC + c) * NST) * DIN + d;
#pragma unroll
    for (int n = 0; n < NST; n++) {
        P[base + (size_t)n * DIN] = __builtin_amdgcn_exp2f(sdt * Aa2[n]);
        S[base + (size_t)n * DIN] = st[n];
    }
}

// parallel over (b, n, d)
__global__ __launch_bounds__(256) void scan_combine(
    const float* __restrict__ P, const float* __restrict__ S,
    float* __restrict__ I)
{
    const int idx = blockIdx.x * 256 + threadIdx.x;
    const int d = idx & (DIN - 1);
    const int n = (idx >> 11) & (NST - 1);
    const int b = idx >> 15;
    float st = 0.f;
#pragma unroll 4
    for (int c = 0; c < NC; c++) {
        const size_t o = ((size_t)((b * NC + c) * NST) + n) * DIN + d;
        float pv = P[o], sv = S[o];
        I[o] = st;
        st = fmaf(pv, st, sv);
    }
}

__global__ __launch_bounds__(256) void scan_pass2(
    const float* __restrict__ dt_lin, const float* __restrict__ dt_b,
    const float* __restrict__ A_log, const float* __restrict__ dbc,
    const float* __restrict__ ssm_in, const float* __restrict__ I,
    const float* __restrict__ D_skip, const float* __restrict__ proj,
    _Float16* __restrict__ scan_out)
{
    const int g = blockIdx.x & 7;
    const int c = (blockIdx.x >> 3) & (NC - 1);
    const int b = blockIdx.x >> 8;
    const int d = g * 256 + threadIdx.x;
    const int row0 = b * L_SZ + c * CL;

    __shared__ float BCs[CL][32];
#pragma unroll
    for (int it = 0; it < (CL * 32) / 256; it++) {
        int i = threadIdx.x + it * 256;
        int l = i >> 5, j = i & 31;
        BCs[l][j] = dbc[(size_t)(row0 + l) * 96 + DTR + j];
    }
    __syncthreads();

    float Aa2[NST];
#pragma unroll
    for (int n = 0; n < NST; n++) Aa2[n] = -exp_fast(A_log[d * NST + n]) * L2E;
    const float dtb = dt_b[d];
    const float dsk = D_skip[d];

    float st[NST];
    const size_t ibase = ((size_t)(b * NC + c) * NST) * DIN + d;
#pragma unroll
    for (int n = 0; n < NST; n++) st[n] = I[ibase + (size_t)n * DIN];

    for (int l = 0; l < CL; l++) {
        const size_t row = (size_t)(row0 + l);
        float dtv = softplus_f(dt_lin[row * DIN + d] + dtb);
        float u = ssm_in[row * DIN + d];
        float du = dtv * u;
        float y = 0.f;
#pragma unroll
        for (int n = 0; n < NST; n++) {
            float dA = __builtin_amdgcn_exp2f(dtv * Aa2[n]);
            st[n] = fmaf(dA, st[n], du * BCs[l][n]);
            y = fmaf(st[n], BCs[l][NST + n], y);
        }
        float gv = proj[row * (2 * DIN) + DIN + d];
        float sg = gv * sigmoid_fast(gv);
        scan_out[row * DIN + d] = (_Float16)((y + u * dsk) * sg);
    }
}

// ---------------------------------------------------------------------------
extern "C" void kernel_launch(void* const* d_in, const int* in_sizes, int n_in,
                              void* d_out, int out_size, void* d_ws, size_t ws_size,
                              hipStream_t stream) {
    const float* x      = (const float*)d_in[0];
    const int*   mask   = (const int*)d_in[1];
    const float* Wq     = (const float*)d_in[2];
    const float* bq     = (const float*)d_in[3];
    const float* Wk     = (const float*)d_in[4];
    const float* bk     = (const float*)d_in[5];
    const float* Wv     = (const float*)d_in[6];
    const float* bv     = (const float*)d_in[7];
    const float* Wo     = (const float*)d_in[8];
    const float* bo     = (const float*)d_in[9];
    const float* ln_w   = (const float*)d_in[10];
    const float* ln_b   = (const float*)d_in[11];
    const float* mnw    = (const float*)d_in[12];
    const float* in_proj_w = (const float*)d_in[13];
    const float* conv_w = (const float*)d_in[14];
    const float* conv_b = (const float*)d_in[15];
    const float* x_proj_w = (const float*)d_in[16];
    const float* dt_proj_w = (const float*)d_in[17];
    const float* dt_proj_b = (const float*)d_in[18];
    const float* A_log  = (const float*)d_in[19];
    const float* D_skip = (const float*)d_in[20];
    const float* out_proj_w = (const float*)d_in[21];
    const float* fnw    = (const float*)d_in[22];
    float* out = (float*)d_out;
    (void)ws_size; (void)n_in; (void)in_sizes; (void)out_size;

    float* ws = (float*)d_ws;
    const size_t F1 = 1u << 20;
    _Float16* Wqkvh = (_Float16*)(ws + 0);
    _Float16* Woh  = (_Float16*)(ws + 3 * F1 / 2);
    _Float16* inph = (_Float16*)(ws + 2 * F1);
    _Float16* outph= (_Float16*)(ws + 4 * F1);
    _Float16* xprh = (_Float16*)(ws + 5 * F1);
    _Float16* dtph = (_Float16*)(ws + 5 * F1 + F1 / 8);
    float* bqkv    = ws + 5 * F1 + 3 * F1 / 16;
    _Float16* xh   = (_Float16*)(ws + 5 * F1 + F1 / 4);
    float* x2      = ws + 6 * F1 + F1 / 4;
    float* proj    = ws + 8 * F1 + F1 / 2;
    float* qkv     = proj;
    float* x3      = proj;
    _Float16* ctxh = (_Float16*)(ws + 16 * F1 + F1 / 2);
    _Float16* dbch = (_Float16*)(ws + 16 * F1 + F1 / 2);
    float* dbc     = ws + 16 * F1 + 3 * F1 / 4;
    float* attn_tmp= ws + 17 * F1 + F1 / 2;
    _Float16* ssmh = (_Float16*)attn_tmp;
    float* Pbuf    = attn_tmp;
    float* Ibuf    = Pbuf;
    _Float16* hh   = (_Float16*)(ws + 19 * F1 + F1 / 2);
    float* ssm     = ws + 20 * F1 + F1 / 2;
    float* dtl     = ws + 24 * F1 + F1 / 2;
    _Float16* qh16 = (_Float16*)(ws + 24 * F1 + F1 / 2);
    _Float16* kh16 = (_Float16*)(ws + 25 * F1 + F1 / 2);
    _Float16* vth16= (_Float16*)(ws + 26 * F1 + F1 / 2);
    float* Sbuf    = ws + 28 * F1 + F1 / 2;
    _Float16* sob  = (_Float16*)Sbuf;

    const int M = B_SZ * L_SZ;
    dim3 blk(256);

    cast_all<<<dim3(CAST_TOTAL / 256), blk, 0, stream>>>(
        Wq, Wk, Wv, Wo, in_proj_w, out_proj_w, dt_proj_w, x, x_proj_w,
        bq, bk, bv, Wqkvh, Woh, inph, outph, dtph, xh, xprh, bqkv);

    hgemm<<<dim3(24, 16), blk, 0, stream>>>(xh, H_SZ, Wqkvh, H_SZ, bqkv, qkv, 3 * H_SZ, 3 * H_SZ, H_SZ);

    repack_attn<<<512, blk, 0, stream>>>(qkv, qh16, kh16, vth16);
    attn_mfma<<<2048, blk, 0, stream>>>(qh16, kh16, vth16, mask, ctxh);

    hgemm<<<dim3(8, 16), blk, 0, stream>>>(ctxh, H_SZ, Woh, H_SZ, bo, attn_tmp, H_SZ, H_SZ, H_SZ);
    add_ln_kernel<<<dim3(M), blk, 0, stream>>>(attn_tmp, x, ln_w, ln_b, x2);

    rmsnorm_h_kernel<<<dim3(M), blk, 0, stream>>>(x2, mnw, hh);
    hgemm<<<dim3(32, 16), blk, 0, stream>>>(hh, H_SZ, inph, H_SZ, nullptr, proj, 2 * DIN, 2 * DIN, H_SZ);

    conv_silu_kernel<<<dim3(B_SZ * L_SZ * DIN / 256), blk, 0, stream>>>(proj, mask, conv_w, conv_b, ssm, ssmh);

    hgemm<<<dim3(1, 16), blk, 0, stream>>>(ssmh, DIN, xprh, DIN, nullptr, dbc, 96, 96, DIN);
    pack_dbc_kernel<<<512, blk, 0, stream>>>(dbc, dbch);
    hgemm<<<dim3(16, 16), blk, 0, stream>>>(dbch, DTR, dtph, DTR, nullptr, dtl, DIN, DIN, DTR);

    scan_pass1<<<dim3(B_SZ * NC * (DIN / 256)), blk, 0, stream>>>(dtl, dt_proj_b, A_log, dbc, ssm, Pbuf, Sbuf);
    scan_combine<<<dim3(B_SZ * NST * DIN / 256), blk, 0, stream>>>(Pbuf, Sbuf, Ibuf);
    scan_pass2<<<dim3(B_SZ * NC * (DIN / 256)), blk, 0, stream>>>(dtl, dt_proj_b, A_log, dbc, ssm, Ibuf, D_skip, proj, sob);

    hgemm<<<dim3(8, 16), blk, 0, stream>>>(sob, DIN, outph, DIN, nullptr, x3, H_SZ, H_SZ, DIN);
    rmsnorm_kernel<<<dim3(M), blk, 0, stream>>>(x2, x3, fnw, out);
}